// Round 1
// baseline (493.904 us; speedup 1.0000x reference)
//
#include <hip/hip_runtime.h>
#include <hip/hip_fp16.h>

#define Bc   2
#define Tc   2048
#define DIMc 1024
#define Hc   16
#define KVHc 4
#define HDc  64
#define Mc   4096   // B*T

typedef unsigned short u16;
typedef __attribute__((ext_vector_type(8))) short short8;
typedef __attribute__((ext_vector_type(8))) __bf16 bf16x8;
typedef __attribute__((ext_vector_type(4))) float f32x4;
typedef __attribute__((ext_vector_type(4))) unsigned short u16x4;

__device__ inline float bf2f(u16 u) {
    unsigned int x = ((unsigned int)u) << 16;
    return __builtin_bit_cast(float, x);
}
__device__ inline u16 f2bf(float f) {  // RNE, no NaNs expected in this pipeline
    unsigned int x = __builtin_bit_cast(unsigned int, f);
    x += 0x7fffu + ((x >> 16) & 1u);
    return (u16)(x >> 16);
}
__device__ inline bf16x8 ld8(const u16* p) {
    return __builtin_bit_cast(bf16x8, *(const short8*)p);
}
__device__ inline f32x4 mfma16(bf16x8 a, bf16x8 b, f32x4 c) {
    return __builtin_amdgcn_mfma_f32_16x16x32_bf16(a, b, c, 0, 0, 0);
}

// ---------------------------------------------------------------------------
// Small transposes: LoRA matrices fp32 -> bf16 transposed (B^T operand layout)
// seg 0..3: qA/kA/vA/pA (1024,32)->(32,1024); seg 4..7: qB/kB/vB/pB (32,N)->(N,32)
// ---------------------------------------------------------------------------
__global__ __launch_bounds__(256) void transpose_small(
    const float* __restrict__ qA, const float* __restrict__ kA,
    const float* __restrict__ vA, const float* __restrict__ pA,
    const float* __restrict__ qB, const float* __restrict__ kB,
    const float* __restrict__ vB, const float* __restrict__ pB,
    u16* __restrict__ AT_all, u16* __restrict__ pAT,
    u16* __restrict__ qBT, u16* __restrict__ kBT,
    u16* __restrict__ vBT, u16* __restrict__ pBT)
{
    const int seg = blockIdx.y;
    const float* src; u16* dst; int R, C;
    switch (seg) {
        case 0: src = qA; dst = AT_all;             R = 1024; C = 32;  break;
        case 1: src = kA; dst = AT_all + 32 * 1024; R = 1024; C = 32;  break;
        case 2: src = vA; dst = AT_all + 64 * 1024; R = 1024; C = 32;  break;
        case 3: src = pA; dst = pAT;                R = 1024; C = 32;  break;
        case 4: src = qB; dst = qBT;                R = 32; C = 1024;  break;
        case 5: src = kB; dst = kBT;                R = 32; C = 256;   break;
        case 6: src = vB; dst = vBT;                R = 32; C = 256;   break;
        default: src = pB; dst = pBT;               R = 32; C = 1024;  break;
    }
    const int idx = blockIdx.x * 256 + threadIdx.x;
    if (idx < R * C) {
        const int r = idx / C, c = idx % C;
        dst[(size_t)c * R + r] = f2bf(src[(size_t)r * C + c]);
    }
}

// ---------------------------------------------------------------------------
// x fp32 -> bf16 (vectorized). Grid exactly covers n/4 threads.
// ---------------------------------------------------------------------------
__global__ __launch_bounds__(256) void cast_f32_bf16(
    const float* __restrict__ src, u16* __restrict__ dst)
{
    const int i = blockIdx.x * 256 + threadIdx.x;
    float4 v = ((const float4*)src)[i];
    u16x4 o = {f2bf(v.x), f2bf(v.y), f2bf(v.z), f2bf(v.w)};
    ((u16x4*)dst)[i] = o;
}

// ---------------------------------------------------------------------------
// Per-row int6 RTN fake-quant with clip-candidate search. One block per row.
// Matches jnp: round = RNE (rintf), s cast fp16->fp32, w_deq = q * s_h.
// ---------------------------------------------------------------------------
__device__ inline float block_sum(float v, volatile float* red) {
    #pragma unroll
    for (int off = 32; off; off >>= 1) v += __shfl_xor(v, off);
    __syncthreads();
    if ((threadIdx.x & 63) == 0) red[threadIdx.x >> 6] = v;
    __syncthreads();
    return red[0] + red[1] + red[2] + red[3];
}
__device__ inline float block_max(float v, volatile float* red) {
    #pragma unroll
    for (int off = 32; off; off >>= 1) v = fmaxf(v, __shfl_xor(v, off));
    __syncthreads();
    if ((threadIdx.x & 63) == 0) red[threadIdx.x >> 6] = v;
    __syncthreads();
    return fmaxf(fmaxf(red[0], red[1]), fmaxf(red[2], red[3]));
}

__global__ __launch_bounds__(256) void quant_rows(
    const float* __restrict__ Wq, const float* __restrict__ Wk,
    const float* __restrict__ Wv, const float* __restrict__ Wo,
    u16* __restrict__ Wqb, u16* __restrict__ Wkb,
    u16* __restrict__ Wvb, u16* __restrict__ Wob)
{
    __shared__ float red[4];
    const int rblk = blockIdx.x;
    const float* src; u16* dst; int rr;
    if (rblk < 1024)      { src = Wq; dst = Wqb; rr = rblk; }
    else if (rblk < 1280) { src = Wk; dst = Wkb; rr = rblk - 1024; }
    else if (rblk < 1536) { src = Wv; dst = Wvb; rr = rblk - 1280; }
    else                  { src = Wo; dst = Wob; rr = rblk - 1536; }
    src += (size_t)rr * DIMc;
    dst += (size_t)rr * DIMc;
    const int tid = threadIdx.x;

    float4 fv = ((const float4*)src)[tid];          // 256 thr x 4 = 1024 cols
    float tv[4] = {fv.x, fv.y, fv.z, fv.w};
    float ps = tv[0] + tv[1] + tv[2] + tv[3];
    float pa = fmaxf(fmaxf(fabsf(tv[0]), fabsf(tv[1])),
                     fmaxf(fabsf(tv[2]), fabsf(tv[3])));
    const float sum  = block_sum(ps, red);
    const float amax = block_max(pa, red);
    const float mean = sum * (1.0f / 1024.0f);
    float psq = 0.f;
    #pragma unroll
    for (int j = 0; j < 4; j++) { float d = tv[j] - mean; psq += d * d; }
    const float var  = block_sum(psq, red) * (1.0f / 1024.0f);
    const float row_std    = fmaxf(sqrtf(var), 1e-8f);
    const float row_absmax = fmaxf(amax, 1.0f / 31.0f);
    const float s1 = fmaxf(fmaxf(row_std * 12.85f, row_absmax * (1.0f / 31.0f)) * (1.0f / 31.0f),
                           1.0f / 31.0f);
    const float s2 = fmaxf(row_absmax * (1.0f / 31.0f), 1.0f / 31.0f);
    float pe1 = 0.f, pe2 = 0.f;
    #pragma unroll
    for (int j = 0; j < 4; j++) {
        float q1 = fminf(fmaxf(rintf(tv[j] / s1), -31.f), 31.f);
        float q2 = fminf(fmaxf(rintf(tv[j] / s2), -31.f), 31.f);
        float d1 = q1 * s1 - tv[j], d2 = q2 * s2 - tv[j];
        pe1 += d1 * d1; pe2 += d2 * d2;
    }
    const float e1 = block_sum(pe1, red);
    const float e2 = block_sum(pe2, red);
    const float ss = (e1 < e2) ? s1 : s2;
    const float sh = __half2float(__float2half(ss));  // fp16 round-trip of scale
    u16x4 outv;
    #pragma unroll
    for (int j = 0; j < 4; j++) {
        float q = fminf(fmaxf(rintf(tv[j] / ss), -31.f), 31.f);
        outv[j] = f2bf(q * sh);
    }
    ((u16x4*)dst)[tid] = outv;
}

// ---------------------------------------------------------------------------
// Generic bf16 MFMA GEMM: C[M,N] = A[M,K] @ B[N,K]^T (+ optional add-input).
// 64x64 tile, 4 waves (2x2), each wave 32x32 via 2x2 of 16x16x32 MFMA.
// LDS rows padded to 40 bf16 to break the stride-64B bank pattern.
// M assumed multiple of 64 and fully valid (always 4096 here); N guarded.
// ---------------------------------------------------------------------------
__global__ __launch_bounds__(256) void gemm64(
    const u16* __restrict__ A, int lda,
    const u16* __restrict__ Bm, int ldb,
    int N, int K,
    float* __restrict__ Cf, const float* __restrict__ Caddf,
    u16* __restrict__ Cb, const u16* __restrict__ Caddb, int ldc)
{
    __shared__ __align__(16) u16 As[64 * 40];
    __shared__ __align__(16) u16 Bs[64 * 40];
    const int tid  = threadIdx.x;
    const int wave = tid >> 6, lane = tid & 63;
    const int quad = lane >> 4, l16 = lane & 15;
    const int wm = wave >> 1, wn = wave & 1;
    const int tileM = blockIdx.y * 64;
    const int tileN = blockIdx.x * 64;
    const int lrow = tid >> 2;        // 0..63
    const int lcol = (tid & 3) * 8;   // 0,8,16,24

    f32x4 acc[2][2] = {};
    const u16* Aptr = A + (size_t)(tileM + lrow) * lda + lcol;
    const u16* Bptr = Bm + (size_t)(tileN + lrow) * ldb + lcol;
    const bool bvalid = (tileN + lrow) < N;

    for (int k0 = 0; k0 < K; k0 += 32) {
        __syncthreads();
        short8 av = *(const short8*)(Aptr + k0);
        short8 bv = {};
        if (bvalid) bv = *(const short8*)(Bptr + k0);
        *(short8*)&As[lrow * 40 + lcol] = av;
        *(short8*)&Bs[lrow * 40 + lcol] = bv;
        __syncthreads();
        bf16x8 a0 = ld8(&As[(wm * 32 + l16) * 40 + quad * 8]);
        bf16x8 a1 = ld8(&As[(wm * 32 + 16 + l16) * 40 + quad * 8]);
        bf16x8 b0 = ld8(&Bs[(wn * 32 + l16) * 40 + quad * 8]);
        bf16x8 b1 = ld8(&Bs[(wn * 32 + 16 + l16) * 40 + quad * 8]);
        acc[0][0] = mfma16(a0, b0, acc[0][0]);
        acc[0][1] = mfma16(a0, b1, acc[0][1]);
        acc[1][0] = mfma16(a1, b0, acc[1][0]);
        acc[1][1] = mfma16(a1, b1, acc[1][1]);
    }
    #pragma unroll
    for (int mi = 0; mi < 2; mi++)
    #pragma unroll
    for (int ni = 0; ni < 2; ni++)
    #pragma unroll
    for (int r = 0; r < 4; r++) {
        const int row = tileM + wm * 32 + mi * 16 + quad * 4 + r;  // C layout: row=quad*4+reg
        const int col = tileN + wn * 32 + ni * 16 + l16;           //           col=lane&15
        if (col < N) {
            float v = acc[mi][ni][r];
            const size_t idx = (size_t)row * ldc + col;
            if (Caddf) v += Caddf[idx];
            if (Caddb) v += bf2f(Caddb[idx]);
            if (Cf) Cf[idx] = v;
            if (Cb) Cb[idx] = f2bf(v);
        }
    }
}

// ---------------------------------------------------------------------------
// RoPE + repack. qin (b,t,H,HD) bf16 -> qatt (b,H,t,HD) with gain*0.125 folded;
// kin -> katt (b,KVH,t,HD); vin -> vatt TRANSPOSED (b,KVH,HD,t) so PV
// B-fragments are contiguous. One block per (b,t).
// ---------------------------------------------------------------------------
__global__ __launch_bounds__(256) void rope_pack(
    const u16* __restrict__ qin, const u16* __restrict__ kin,
    const u16* __restrict__ vin, const float* __restrict__ q_gain,
    u16* __restrict__ qatt, u16* __restrict__ katt, u16* __restrict__ vatt)
{
    const int i = blockIdx.x;             // b*T + t
    const int b = i >> 11, t = i & (Tc - 1);
    const int tid = threadIdx.x;
    const float L2B = 0.41524101186092035f;   // log2(10000)/32

    for (int pi = tid; pi < Hc * 32; pi += 256) {
        const int h = pi >> 5, p = pi & 31;
        const float x1 = bf2f(qin[(size_t)i * DIMc + h * HDc + p]);
        const float x2 = bf2f(qin[(size_t)i * DIMc + h * HDc + 32 + p]);
        const float fr = (float)t * exp2f(-L2B * (float)p);
        float s, c; sincosf(fr, &s, &c);
        const float g = q_gain[h] * 0.125f;   // fold 1/sqrt(HD) into q
        const size_t o = ((size_t)(b * Hc + h) * Tc + t) * HDc + p;
        qatt[o]      = f2bf((x1 * c + x2 * s) * g);
        qatt[o + 32] = f2bf((x2 * c - x1 * s) * g);
    }
    for (int pi = tid; pi < KVHc * 32; pi += 256) {
        const int kh = pi >> 5, p = pi & 31;
        const float x1 = bf2f(kin[(size_t)i * (KVHc * HDc) + kh * HDc + p]);
        const float x2 = bf2f(kin[(size_t)i * (KVHc * HDc) + kh * HDc + 32 + p]);
        const float fr = (float)t * exp2f(-L2B * (float)p);
        float s, c; sincosf(fr, &s, &c);
        const size_t o = ((size_t)(b * KVHc + kh) * Tc + t) * HDc + p;
        katt[o]      = f2bf(x1 * c + x2 * s);
        katt[o + 32] = f2bf(x2 * c - x1 * s);
    }
    for (int e = tid; e < KVHc * HDc; e += 256) {
        const int kh = e >> 6, hd = e & 63;
        vatt[((size_t)(b * KVHc + kh) * HDc + hd) * Tc + t] =
            vin[(size_t)i * (KVHc * HDc) + e];
    }
}

// ---------------------------------------------------------------------------
// Flash attention. Block = 4 waves; wave owns 16 q-rows; K-tiles of 32.
// QK^T: Q as A-frag, K rows as B-frag (both K-dim contiguous).
// P: C-layout -> LDS (pad stride 40) -> A-frag.  PV: V^T rows as B-frag.
// Online softmax in fp32; head_gate folded into epilogue; writes y bf16
// in (b,t,H,HD) layout for the o-projection GEMM.
// ---------------------------------------------------------------------------
__global__ __launch_bounds__(256) void flash_attn(
    const u16* __restrict__ qatt, const u16* __restrict__ katt,
    const u16* __restrict__ vatt, const float* __restrict__ head_gate,
    u16* __restrict__ ybf)
{
    __shared__ __align__(16) u16 plds[4][16 * 40];
    const int tid = threadIdx.x;
    const int wave = tid >> 6, lane = tid & 63;
    const int quad = lane >> 4, l16 = lane & 15;
    const int bh = blockIdx.y;
    const int b = bh / Hc, h = bh % Hc;
    const int kvh = h >> 2;                    // rep = H/KVH = 4
    const int qb = blockIdx.x * 64 + wave * 16;

    const u16* qbase = qatt + ((size_t)((b * Hc + h) * Tc + qb + l16)) * HDc;
    const bf16x8 aq0 = ld8(qbase + quad * 8);
    const bf16x8 aq1 = ld8(qbase + 32 + quad * 8);

    const u16* kbase = katt + (size_t)(b * KVHc + kvh) * Tc * HDc;
    const u16* vbase = vatt + (size_t)(b * KVHc + kvh) * HDc * Tc;

    float m_run[4], l_run[4];
    f32x4 o[4] = {};
    #pragma unroll
    for (int r = 0; r < 4; r++) { m_run[r] = -3.0e38f; l_run[r] = 0.f; }

    u16* pw = plds[wave];
    const int ktmax = (qb + 15) >> 5;
    for (int kt = 0; kt <= ktmax; kt++) {
        const u16* kp = kbase + (size_t)(kt * 32 + l16) * HDc + quad * 8;
        const bf16x8 k00 = ld8(kp);
        const bf16x8 k01 = ld8(kp + 32);
        const bf16x8 k10 = ld8(kp + 16 * HDc);
        const bf16x8 k11 = ld8(kp + 16 * HDc + 32);
        f32x4 s0 = {}, s1 = {};
        s0 = mfma16(aq0, k00, s0); s0 = mfma16(aq1, k01, s0);
        s1 = mfma16(aq0, k10, s1); s1 = mfma16(aq1, k11, s1);

        const bool need_mask = (kt * 32 + 31) > qb;
        const int kc0 = kt * 32 + l16, kc1 = kt * 32 + 16 + l16;
        float alpha[4], p0[4], p1[4];
        #pragma unroll
        for (int r = 0; r < 4; r++) {
            float v0 = s0[r], v1 = s1[r];          // 0.125 already folded into q
            if (need_mask) {
                const int qrow = qb + quad * 4 + r;
                if (kc0 > qrow) v0 = -1e30f;
                if (kc1 > qrow) v1 = -1e30f;
            }
            float mt = fmaxf(v0, v1);
            #pragma unroll
            for (int off = 1; off < 16; off <<= 1) mt = fmaxf(mt, __shfl_xor(mt, off, 16));
            const float mn = fmaxf(m_run[r], mt);
            alpha[r] = __expf(m_run[r] - mn);
            m_run[r] = mn;
            p0[r] = __expf(v0 - mn);
            p1[r] = __expf(v1 - mn);
            float rs = p0[r] + p1[r];
            #pragma unroll
            for (int off = 1; off < 16; off <<= 1) rs += __shfl_xor(rs, off, 16);
            l_run[r] = l_run[r] * alpha[r] + rs;
        }
        #pragma unroll
        for (int f = 0; f < 4; f++)
            #pragma unroll
            for (int r = 0; r < 4; r++) o[f][r] *= alpha[r];

        // P (C layout) -> LDS -> A-frag (wave-private region; no barrier needed)
        #pragma unroll
        for (int r = 0; r < 4; r++) {
            pw[(quad * 4 + r) * 40 + l16]      = f2bf(p0[r]);
            pw[(quad * 4 + r) * 40 + 16 + l16] = f2bf(p1[r]);
        }
        const bf16x8 pa = ld8(&pw[l16 * 40 + quad * 8]);

        const u16* vp = vbase + (size_t)l16 * Tc + kt * 32 + quad * 8;
        #pragma unroll
        for (int f = 0; f < 4; f++) {
            const bf16x8 vb = ld8(vp + (size_t)(f * 16) * Tc);
            o[f] = mfma16(pa, vb, o[f]);
        }
    }
    const float g = head_gate[h];
    #pragma unroll
    for (int r = 0; r < 4; r++) {
        const int qrow = qb + quad * 4 + r;
        const float inv = g / l_run[r];
        u16* yb = ybf + (size_t)(b * Tc + qrow) * DIMc + h * HDc + l16;
        #pragma unroll
        for (int f = 0; f < 4; f++) yb[f * 16] = f2bf(o[f][r] * inv);
    }
}

// ---------------------------------------------------------------------------
extern "C" void kernel_launch(void* const* d_in, const int* in_sizes, int n_in,
                              void* d_out, int out_size, void* d_ws, size_t ws_size,
                              hipStream_t stream) {
    (void)in_sizes; (void)n_in; (void)out_size; (void)ws_size;
    const float* x    = (const float*)d_in[0];
    const float* Wq   = (const float*)d_in[1];
    const float* Wk   = (const float*)d_in[2];
    const float* Wv   = (const float*)d_in[3];
    const float* Wo   = (const float*)d_in[4];
    const float* qA   = (const float*)d_in[5];
    const float* qB   = (const float*)d_in[6];
    const float* kA   = (const float*)d_in[7];
    const float* kB   = (const float*)d_in[8];
    const float* vA   = (const float*)d_in[9];
    const float* vB   = (const float*)d_in[10];
    const float* pA   = (const float*)d_in[11];
    const float* pB   = (const float*)d_in[12];
    const float* q_gain    = (const float*)d_in[13];
    const float* head_gate = (const float*)d_in[14];
    float* out = (float*)d_out;

    char* wsp = (char*)d_ws;
    size_t off = 0;
    auto alloc = [&](size_t bytes) -> void* {
        void* p = wsp + off;
        off = (off + bytes + 255) & ~(size_t)255;
        return p;
    };
    u16* x_bf   = (u16*)alloc((size_t)Mc * DIMc * 2);
    u16* Wq_b   = (u16*)alloc((size_t)DIMc * DIMc * 2);
    u16* Wk_b   = (u16*)alloc((size_t)256 * DIMc * 2);
    u16* Wv_b   = (u16*)alloc((size_t)256 * DIMc * 2);
    u16* Wo_b   = (u16*)alloc((size_t)DIMc * DIMc * 2);
    u16* AT_all = (u16*)alloc((size_t)96 * 1024 * 2);
    u16* pAT    = (u16*)alloc((size_t)32 * 1024 * 2);
    u16* qBT    = (u16*)alloc((size_t)1024 * 32 * 2);
    u16* kBT    = (u16*)alloc((size_t)256 * 32 * 2);
    u16* vBT    = (u16*)alloc((size_t)256 * 32 * 2);
    u16* pBT    = (u16*)alloc((size_t)1024 * 32 * 2);
    u16* xA     = (u16*)alloc((size_t)Mc * 96 * 2);
    u16* q_bf   = (u16*)alloc((size_t)Mc * DIMc * 2);
    u16* k_bf   = (u16*)alloc((size_t)Mc * 256 * 2);
    u16* v_bf   = (u16*)alloc((size_t)Mc * 256 * 2);
    u16* qatt   = (u16*)alloc((size_t)Mc * DIMc * 2);
    u16* katt   = (u16*)alloc((size_t)Mc * 256 * 2);
    u16* vatt   = (u16*)alloc((size_t)Mc * 256 * 2);
    u16* y_bf   = (u16*)alloc((size_t)Mc * DIMc * 2);
    u16* yA     = (u16*)alloc((size_t)Mc * 32 * 2);

    // prep
    transpose_small<<<dim3(128, 8), 256, 0, stream>>>(qA, kA, vA, pA, qB, kB, vB, pB,
                                                      AT_all, pAT, qBT, kBT, vBT, pBT);
    cast_f32_bf16<<<Mc * DIMc / 1024, 256, 0, stream>>>(x, x_bf);
    quant_rows<<<2560, 256, 0, stream>>>(Wq, Wk, Wv, Wo, Wq_b, Wk_b, Wv_b, Wo_b);

    // LoRA stage 1: xA = x @ [qA|kA|vA]  (M=4096, N=96, K=1024), bf16 out
    gemm64<<<dim3(2, 64), 256, 0, stream>>>(x_bf, DIMc, AT_all, 1024, 96, 1024,
                                            nullptr, nullptr, xA, nullptr, 96);
    // q = xA_q @ qB, then += x @ Wq_deq^T
    gemm64<<<dim3(16, 64), 256, 0, stream>>>(xA, 96, qBT, 32, 1024, 32,
                                             nullptr, nullptr, q_bf, nullptr, DIMc);
    gemm64<<<dim3(16, 64), 256, 0, stream>>>(x_bf, DIMc, Wq_b, DIMc, 1024, 1024,
                                             nullptr, nullptr, q_bf, q_bf, DIMc);
    // k
    gemm64<<<dim3(4, 64), 256, 0, stream>>>(xA + 32, 96, kBT, 32, 256, 32,
                                            nullptr, nullptr, k_bf, nullptr, 256);
    gemm64<<<dim3(4, 64), 256, 0, stream>>>(x_bf, DIMc, Wk_b, DIMc, 256, 1024,
                                            nullptr, nullptr, k_bf, k_bf, 256);
    // v
    gemm64<<<dim3(4, 64), 256, 0, stream>>>(xA + 64, 96, vBT, 32, 256, 32,
                                            nullptr, nullptr, v_bf, nullptr, 256);
    gemm64<<<dim3(4, 64), 256, 0, stream>>>(x_bf, DIMc, Wv_b, DIMc, 256, 1024,
                                            nullptr, nullptr, v_bf, v_bf, 256);

    rope_pack<<<Mc, 256, 0, stream>>>(q_bf, k_bf, v_bf, q_gain, qatt, katt, vatt);
    flash_attn<<<dim3(Tc / 64, Bc * Hc), 256, 0, stream>>>(qatt, katt, vatt, head_gate, y_bf);

    // output projection: out = yA_p @ pB, then += y @ Wo_deq^T
    gemm64<<<dim3(1, 64), 256, 0, stream>>>(y_bf, DIMc, pAT, 1024, 32, 1024,
                                            nullptr, nullptr, yA, nullptr, 32);
    gemm64<<<dim3(16, 64), 256, 0, stream>>>(yA, 32, pBT, 32, 1024, 32,
                                             out, nullptr, nullptr, nullptr, DIMc);
    gemm64<<<dim3(16, 64), 256, 0, stream>>>(y_bf, DIMc, Wo_b, DIMc, 1024, 1024,
                                             out, out, nullptr, nullptr, DIMc);
}

// Round 2
// 381.515 us; speedup vs baseline: 1.2946x; 1.2946x over previous
//
#include <hip/hip_runtime.h>
#include <hip/hip_fp16.h>

#define Bc   2
#define Tc   2048
#define DIMc 1024
#define Hc   16
#define KVHc 4
#define HDc  64
#define Mc   4096   // B*T

typedef unsigned short u16;
typedef __attribute__((ext_vector_type(8))) short short8;
typedef __attribute__((ext_vector_type(8))) __bf16 bf16x8;
typedef __attribute__((ext_vector_type(4))) float f32x4;
typedef __attribute__((ext_vector_type(4))) unsigned short u16x4;

__device__ inline float bf2f(u16 u) {
    unsigned int x = ((unsigned int)u) << 16;
    return __builtin_bit_cast(float, x);
}
__device__ inline u16 f2bf(float f) {  // RNE, no NaNs expected in this pipeline
    unsigned int x = __builtin_bit_cast(unsigned int, f);
    x += 0x7fffu + ((x >> 16) & 1u);
    return (u16)(x >> 16);
}
__device__ inline bf16x8 ld8(const u16* p) {
    return __builtin_bit_cast(bf16x8, *(const short8*)p);
}
__device__ inline f32x4 mfma16(bf16x8 a, bf16x8 b, f32x4 c) {
    return __builtin_amdgcn_mfma_f32_16x16x32_bf16(a, b, c, 0, 0, 0);
}

// ---------------------------------------------------------------------------
// Small transposes: LoRA matrices fp32 -> bf16 transposed (B^T operand layout)
// seg 0..3: qA/kA/vA/pA (1024,32)->(32,1024); seg 4..7: qB/kB/vB/pB (32,N)->(N,32)
// ---------------------------------------------------------------------------
__global__ __launch_bounds__(256) void transpose_small(
    const float* __restrict__ qA, const float* __restrict__ kA,
    const float* __restrict__ vA, const float* __restrict__ pA,
    const float* __restrict__ qB, const float* __restrict__ kB,
    const float* __restrict__ vB, const float* __restrict__ pB,
    u16* __restrict__ AT_all, u16* __restrict__ pAT,
    u16* __restrict__ qBT, u16* __restrict__ kBT,
    u16* __restrict__ vBT, u16* __restrict__ pBT)
{
    const int seg = blockIdx.y;
    const float* src; u16* dst; int R, C;
    switch (seg) {
        case 0: src = qA; dst = AT_all;             R = 1024; C = 32;  break;
        case 1: src = kA; dst = AT_all + 32 * 1024; R = 1024; C = 32;  break;
        case 2: src = vA; dst = AT_all + 64 * 1024; R = 1024; C = 32;  break;
        case 3: src = pA; dst = pAT;                R = 1024; C = 32;  break;
        case 4: src = qB; dst = qBT;                R = 32; C = 1024;  break;
        case 5: src = kB; dst = kBT;                R = 32; C = 256;   break;
        case 6: src = vB; dst = vBT;                R = 32; C = 256;   break;
        default: src = pB; dst = pBT;               R = 32; C = 1024;  break;
    }
    const int idx = blockIdx.x * 256 + threadIdx.x;
    if (idx < R * C) {
        const int r = idx / C, c = idx % C;
        dst[(size_t)c * R + r] = f2bf(src[(size_t)r * C + c]);
    }
}

// ---------------------------------------------------------------------------
// x fp32 -> bf16 (vectorized). Grid exactly covers n/4 threads.
// ---------------------------------------------------------------------------
__global__ __launch_bounds__(256) void cast_f32_bf16(
    const float* __restrict__ src, u16* __restrict__ dst)
{
    const int i = blockIdx.x * 256 + threadIdx.x;
    float4 v = ((const float4*)src)[i];
    u16x4 o = {f2bf(v.x), f2bf(v.y), f2bf(v.z), f2bf(v.w)};
    ((u16x4*)dst)[i] = o;
}

// ---------------------------------------------------------------------------
// Per-row int6 RTN fake-quant with clip-candidate search. One block per row.
// Matches jnp: round = RNE (rintf), s cast fp16->fp32, w_deq = q * s_h.
// ---------------------------------------------------------------------------
__device__ inline float block_sum(float v, volatile float* red) {
    #pragma unroll
    for (int off = 32; off; off >>= 1) v += __shfl_xor(v, off);
    __syncthreads();
    if ((threadIdx.x & 63) == 0) red[threadIdx.x >> 6] = v;
    __syncthreads();
    return red[0] + red[1] + red[2] + red[3];
}
__device__ inline float block_max(float v, volatile float* red) {
    #pragma unroll
    for (int off = 32; off; off >>= 1) v = fmaxf(v, __shfl_xor(v, off));
    __syncthreads();
    if ((threadIdx.x & 63) == 0) red[threadIdx.x >> 6] = v;
    __syncthreads();
    return fmaxf(fmaxf(red[0], red[1]), fmaxf(red[2], red[3]));
}

__global__ __launch_bounds__(256) void quant_rows(
    const float* __restrict__ Wq, const float* __restrict__ Wk,
    const float* __restrict__ Wv, const float* __restrict__ Wo,
    u16* __restrict__ Wqb, u16* __restrict__ Wkb,
    u16* __restrict__ Wvb, u16* __restrict__ Wob)
{
    __shared__ float red[4];
    const int rblk = blockIdx.x;
    const float* src; u16* dst; int rr;
    if (rblk < 1024)      { src = Wq; dst = Wqb; rr = rblk; }
    else if (rblk < 1280) { src = Wk; dst = Wkb; rr = rblk - 1024; }
    else if (rblk < 1536) { src = Wv; dst = Wvb; rr = rblk - 1280; }
    else                  { src = Wo; dst = Wob; rr = rblk - 1536; }
    src += (size_t)rr * DIMc;
    dst += (size_t)rr * DIMc;
    const int tid = threadIdx.x;

    float4 fv = ((const float4*)src)[tid];          // 256 thr x 4 = 1024 cols
    float tv[4] = {fv.x, fv.y, fv.z, fv.w};
    float ps = tv[0] + tv[1] + tv[2] + tv[3];
    float pa = fmaxf(fmaxf(fabsf(tv[0]), fabsf(tv[1])),
                     fmaxf(fabsf(tv[2]), fabsf(tv[3])));
    const float sum  = block_sum(ps, red);
    const float amax = block_max(pa, red);
    const float mean = sum * (1.0f / 1024.0f);
    float psq = 0.f;
    #pragma unroll
    for (int j = 0; j < 4; j++) { float d = tv[j] - mean; psq += d * d; }
    const float var  = block_sum(psq, red) * (1.0f / 1024.0f);
    const float row_std    = fmaxf(sqrtf(var), 1e-8f);
    const float row_absmax = fmaxf(amax, 1.0f / 31.0f);
    const float s1 = fmaxf(fmaxf(row_std * 12.85f, row_absmax * (1.0f / 31.0f)) * (1.0f / 31.0f),
                           1.0f / 31.0f);
    const float s2 = fmaxf(row_absmax * (1.0f / 31.0f), 1.0f / 31.0f);
    float pe1 = 0.f, pe2 = 0.f;
    #pragma unroll
    for (int j = 0; j < 4; j++) {
        float q1 = fminf(fmaxf(rintf(tv[j] / s1), -31.f), 31.f);
        float q2 = fminf(fmaxf(rintf(tv[j] / s2), -31.f), 31.f);
        float d1 = q1 * s1 - tv[j], d2 = q2 * s2 - tv[j];
        pe1 += d1 * d1; pe2 += d2 * d2;
    }
    const float e1 = block_sum(pe1, red);
    const float e2 = block_sum(pe2, red);
    const float ss = (e1 < e2) ? s1 : s2;
    const float sh = __half2float(__float2half(ss));  // fp16 round-trip of scale
    u16x4 outv;
    #pragma unroll
    for (int j = 0; j < 4; j++) {
        float q = fminf(fmaxf(rintf(tv[j] / ss), -31.f), 31.f);
        outv[j] = f2bf(q * sh);
    }
    ((u16x4*)dst)[tid] = outv;
}

// ---------------------------------------------------------------------------
// Generic bf16 MFMA GEMM: C[M,N] = A[M,K] @ B[N,K]^T (+ optional fused second
// K=32 segment: += A2[M,32] @ B2[N,32]^T, for LoRA) (+ optional add-input).
// 64x64 tile, 4 waves (2x2), each wave 32x32 via 2x2 of 16x16x32 MFMA.
// LDS rows padded to 40 bf16 to break the stride-64B bank pattern.
// M assumed multiple of 64 and fully valid (always 4096 here); N guarded.
// ---------------------------------------------------------------------------
__global__ __launch_bounds__(256) void gemm64(
    const u16* __restrict__ A, int lda,
    const u16* __restrict__ Bm, int ldb,
    int N, int K,
    const u16* __restrict__ A2, int lda2,
    const u16* __restrict__ B2, int ldb2,
    float* __restrict__ Cf, const float* __restrict__ Caddf,
    u16* __restrict__ Cb, const u16* __restrict__ Caddb, int ldc)
{
    __shared__ __align__(16) u16 As[64 * 40];
    __shared__ __align__(16) u16 Bs[64 * 40];
    const int tid  = threadIdx.x;
    const int wave = tid >> 6, lane = tid & 63;
    const int quad = lane >> 4, l16 = lane & 15;
    const int wm = wave >> 1, wn = wave & 1;
    const int tileM = blockIdx.y * 64;
    const int tileN = blockIdx.x * 64;
    const int lrow = tid >> 2;        // 0..63
    const int lcol = (tid & 3) * 8;   // 0,8,16,24

    f32x4 acc[2][2] = {};
    const u16* Aptr = A + (size_t)(tileM + lrow) * lda + lcol;
    const u16* Bptr = Bm + (size_t)(tileN + lrow) * ldb + lcol;
    const bool bvalid = (tileN + lrow) < N;

    for (int k0 = 0; k0 < K; k0 += 32) {
        __syncthreads();
        short8 av = *(const short8*)(Aptr + k0);
        short8 bv = {};
        if (bvalid) bv = *(const short8*)(Bptr + k0);
        *(short8*)&As[lrow * 40 + lcol] = av;
        *(short8*)&Bs[lrow * 40 + lcol] = bv;
        __syncthreads();
        bf16x8 a0 = ld8(&As[(wm * 32 + l16) * 40 + quad * 8]);
        bf16x8 a1 = ld8(&As[(wm * 32 + 16 + l16) * 40 + quad * 8]);
        bf16x8 b0 = ld8(&Bs[(wn * 32 + l16) * 40 + quad * 8]);
        bf16x8 b1 = ld8(&Bs[(wn * 32 + 16 + l16) * 40 + quad * 8]);
        acc[0][0] = mfma16(a0, b0, acc[0][0]);
        acc[0][1] = mfma16(a0, b1, acc[0][1]);
        acc[1][0] = mfma16(a1, b0, acc[1][0]);
        acc[1][1] = mfma16(a1, b1, acc[1][1]);
    }
    if (A2) {  // fused LoRA K=32 segment: lcol in {0,8,16,24} covers K2 exactly
        __syncthreads();
        short8 av = *(const short8*)(A2 + (size_t)(tileM + lrow) * lda2 + lcol);
        short8 bv = {};
        if (bvalid) bv = *(const short8*)(B2 + (size_t)(tileN + lrow) * ldb2 + lcol);
        *(short8*)&As[lrow * 40 + lcol] = av;
        *(short8*)&Bs[lrow * 40 + lcol] = bv;
        __syncthreads();
        bf16x8 a0 = ld8(&As[(wm * 32 + l16) * 40 + quad * 8]);
        bf16x8 a1 = ld8(&As[(wm * 32 + 16 + l16) * 40 + quad * 8]);
        bf16x8 b0 = ld8(&Bs[(wn * 32 + l16) * 40 + quad * 8]);
        bf16x8 b1 = ld8(&Bs[(wn * 32 + 16 + l16) * 40 + quad * 8]);
        acc[0][0] = mfma16(a0, b0, acc[0][0]);
        acc[0][1] = mfma16(a0, b1, acc[0][1]);
        acc[1][0] = mfma16(a1, b0, acc[1][0]);
        acc[1][1] = mfma16(a1, b1, acc[1][1]);
    }
    #pragma unroll
    for (int mi = 0; mi < 2; mi++)
    #pragma unroll
    for (int ni = 0; ni < 2; ni++)
    #pragma unroll
    for (int r = 0; r < 4; r++) {
        const int row = tileM + wm * 32 + mi * 16 + quad * 4 + r;  // C layout: row=quad*4+reg
        const int col = tileN + wn * 32 + ni * 16 + l16;           //           col=lane&15
        if (col < N) {
            float v = acc[mi][ni][r];
            const size_t idx = (size_t)row * ldc + col;
            if (Caddf) v += Caddf[idx];
            if (Caddb) v += bf2f(Caddb[idx]);
            if (Cf) Cf[idx] = v;
            if (Cb) Cb[idx] = f2bf(v);
        }
    }
}

// ---------------------------------------------------------------------------
// RoPE + repack. qin (b,t,H,HD) bf16 -> qatt (b,H,t,HD) with gain*0.125 folded;
// kin -> katt (b,KVH,t,HD); vin -> vatt TRANSPOSED (b,KVH,HD,t) so PV
// B-fragments are contiguous. One block per (b,t).
// ---------------------------------------------------------------------------
__global__ __launch_bounds__(256) void rope_pack(
    const u16* __restrict__ qin, const u16* __restrict__ kin,
    const u16* __restrict__ vin, const float* __restrict__ q_gain,
    u16* __restrict__ qatt, u16* __restrict__ katt, u16* __restrict__ vatt)
{
    const int i = blockIdx.x;             // b*T + t
    const int b = i >> 11, t = i & (Tc - 1);
    const int tid = threadIdx.x;
    const float L2B = 0.41524101186092035f;   // log2(10000)/32

    for (int pi = tid; pi < Hc * 32; pi += 256) {
        const int h = pi >> 5, p = pi & 31;
        const float x1 = bf2f(qin[(size_t)i * DIMc + h * HDc + p]);
        const float x2 = bf2f(qin[(size_t)i * DIMc + h * HDc + 32 + p]);
        const float fr = (float)t * exp2f(-L2B * (float)p);
        float s, c; sincosf(fr, &s, &c);
        const float g = q_gain[h] * 0.125f;   // fold 1/sqrt(HD) into q
        const size_t o = ((size_t)(b * Hc + h) * Tc + t) * HDc + p;
        qatt[o]      = f2bf((x1 * c + x2 * s) * g);
        qatt[o + 32] = f2bf((x2 * c - x1 * s) * g);
    }
    for (int pi = tid; pi < KVHc * 32; pi += 256) {
        const int kh = pi >> 5, p = pi & 31;
        const float x1 = bf2f(kin[(size_t)i * (KVHc * HDc) + kh * HDc + p]);
        const float x2 = bf2f(kin[(size_t)i * (KVHc * HDc) + kh * HDc + 32 + p]);
        const float fr = (float)t * exp2f(-L2B * (float)p);
        float s, c; sincosf(fr, &s, &c);
        const size_t o = ((size_t)(b * KVHc + kh) * Tc + t) * HDc + p;
        katt[o]      = f2bf(x1 * c + x2 * s);
        katt[o + 32] = f2bf(x2 * c - x1 * s);
    }
    for (int e = tid; e < KVHc * HDc; e += 256) {
        const int kh = e >> 6, hd = e & 63;
        vatt[((size_t)(b * KVHc + kh) * HDc + hd) * Tc + t] =
            vin[(size_t)i * (KVHc * HDc) + e];
    }
}

// ---------------------------------------------------------------------------
// Flash attention v2. Wave owns 16 q-rows; K-tiles of 64.
// S^T = K @ Q^T   (A=K rows, B=Q rows)  -> C col = q (lane&15), row = key.
//   Row-softmax = in-register tree over 16 vals + 2 shfl_xor (16,32).
// O^T = V @ P^T   (A=V^T rows, B=P from LDS; A/B frag layouts identical)
//   -> C col = q: alpha/l rescale is IN-LANE, epilogue is packed 8B stores.
// Wave<->q-tile interleave (j = x + wave*32, flipped by bh&1) balances the
// causal triangle across CUs/XCDs. All LDS wave-private: zero barriers.
// ---------------------------------------------------------------------------
__global__ __launch_bounds__(256) void flash_attn2(
    const u16* __restrict__ qatt, const u16* __restrict__ katt,
    const u16* __restrict__ vatt, const float* __restrict__ head_gate,
    u16* __restrict__ ybf)
{
    __shared__ __align__(16) u16 plds[4][16 * 72];   // 16 q rows x 64 keys, pad 72
    const int tid = threadIdx.x;
    const int wave = tid >> 6, lane = tid & 63;
    const int quad = lane >> 4, l16 = lane & 15;
    const int bh = blockIdx.y;
    const int b = bh >> 4, h = bh & 15;
    const int kvh = h >> 2;                    // rep = H/KVH = 4
    const int xx = (bh & 1) ? (31 - (int)blockIdx.x) : (int)blockIdx.x;
    const int j = xx + wave * 32;              // q-tile 0..127 (16 rows each)
    const int qw = j * 16;

    const u16* qbase = qatt + ((size_t)((b * Hc + h) * Tc + qw + l16)) * HDc;
    const bf16x8 bq0 = ld8(qbase + quad * 8);        // B-frag: n=q, k=d 0..31
    const bf16x8 bq1 = ld8(qbase + 32 + quad * 8);   //               d 32..63

    const u16* kbase = katt + (size_t)(b * KVHc + kvh) * Tc * HDc;
    const u16* vbase = vatt + (size_t)(b * KVHc + kvh) * HDc * Tc;

    float m_run = -3.0e38f, l_run = 0.f;
    f32x4 o[4] = {};                    // O^T: col=q(l16), row=hd f*16+quad*4+r
    u16* pw = plds[wave];

    const int ktmax = (qw + 15) >> 6;
    for (int kt = 0; kt <= ktmax; kt++) {
        const int k0 = kt * 64;
        f32x4 st[4];
        #pragma unroll
        for (int ft = 0; ft < 4; ft++) {
            const u16* kp = kbase + (size_t)(k0 + ft * 16 + l16) * HDc + quad * 8;
            bf16x8 a0 = ld8(kp);          // A-frag: m=key, k=d
            bf16x8 a1 = ld8(kp + 32);
            f32x4 s = {};
            s = mfma16(a0, bq0, s);
            s = mfma16(a1, bq1, s);
            st[ft] = s;                   // col=q(l16), row=key k0+ft*16+quad*4+r
        }
        if (k0 + 63 > qw) {               // diagonal tile: causal mask
            const int qrow = qw + l16;
            #pragma unroll
            for (int ft = 0; ft < 4; ft++)
                #pragma unroll
                for (int r = 0; r < 4; r++)
                    if (k0 + ft * 16 + quad * 4 + r > qrow) st[ft][r] = -1e30f;
        }
        // per-q max: in-register tree + 2 cross-quad shuffles
        float vm = fmaxf(fmaxf(st[0][0], st[0][1]), fmaxf(st[0][2], st[0][3]));
        #pragma unroll
        for (int ft = 1; ft < 4; ft++)
            vm = fmaxf(vm, fmaxf(fmaxf(st[ft][0], st[ft][1]),
                                 fmaxf(st[ft][2], st[ft][3])));
        vm = fmaxf(vm, __shfl_xor(vm, 16));
        vm = fmaxf(vm, __shfl_xor(vm, 32));
        const float mnew = fmaxf(m_run, vm);
        const float alpha = __expf(m_run - mnew);
        m_run = mnew;

        float psum = 0.f;
        #pragma unroll
        for (int ft = 0; ft < 4; ft++) {
            float p0 = __expf(st[ft][0] - mnew);
            float p1 = __expf(st[ft][1] - mnew);
            float p2 = __expf(st[ft][2] - mnew);
            float p3 = __expf(st[ft][3] - mnew);
            psum += (p0 + p1) + (p2 + p3);
            u16x4 pk = {f2bf(p0), f2bf(p1), f2bf(p2), f2bf(p3)};
            *(u16x4*)&pw[l16 * 72 + ft * 16 + quad * 4] = pk;   // P[q][key]
        }
        psum += __shfl_xor(psum, 16);
        psum += __shfl_xor(psum, 32);
        l_run = l_run * alpha + psum;

        #pragma unroll
        for (int f = 0; f < 4; f++) {
            o[f][0] *= alpha; o[f][1] *= alpha;
            o[f][2] *= alpha; o[f][3] *= alpha;
        }
        // P back as B-frag (identical layout to A-frag): n=q(l16), k=key
        const bf16x8 pa0 = ld8(&pw[l16 * 72 + quad * 8]);
        const bf16x8 pa1 = ld8(&pw[l16 * 72 + 32 + quad * 8]);
        #pragma unroll
        for (int f = 0; f < 4; f++) {
            const u16* vp = vbase + (size_t)(f * 16 + l16) * Tc + k0 + quad * 8;
            const bf16x8 v0 = ld8(vp);        // A-frag: m=hd, k=key
            const bf16x8 v1 = ld8(vp + 32);
            o[f] = mfma16(v0, pa0, o[f]);     // O^T += V * P^T
            o[f] = mfma16(v1, pa1, o[f]);
        }
    }
    const float inv = head_gate[h] / l_run;       // per-q, in-lane (q = l16)
    u16* yb = ybf + ((size_t)(b * Tc + qw + l16)) * DIMc + h * HDc + quad * 4;
    #pragma unroll
    for (int f = 0; f < 4; f++) {
        u16x4 pk = {f2bf(o[f][0] * inv), f2bf(o[f][1] * inv),
                    f2bf(o[f][2] * inv), f2bf(o[f][3] * inv)};
        *(u16x4*)(yb + f * 16) = pk;
    }
}

// ---------------------------------------------------------------------------
extern "C" void kernel_launch(void* const* d_in, const int* in_sizes, int n_in,
                              void* d_out, int out_size, void* d_ws, size_t ws_size,
                              hipStream_t stream) {
    (void)in_sizes; (void)n_in; (void)out_size; (void)ws_size;
    const float* x    = (const float*)d_in[0];
    const float* Wq   = (const float*)d_in[1];
    const float* Wk   = (const float*)d_in[2];
    const float* Wv   = (const float*)d_in[3];
    const float* Wo   = (const float*)d_in[4];
    const float* qA   = (const float*)d_in[5];
    const float* qB   = (const float*)d_in[6];
    const float* kA   = (const float*)d_in[7];
    const float* kB   = (const float*)d_in[8];
    const float* vA   = (const float*)d_in[9];
    const float* vB   = (const float*)d_in[10];
    const float* pA   = (const float*)d_in[11];
    const float* pB   = (const float*)d_in[12];
    const float* q_gain    = (const float*)d_in[13];
    const float* head_gate = (const float*)d_in[14];
    float* out = (float*)d_out;

    char* wsp = (char*)d_ws;
    size_t off = 0;
    auto alloc = [&](size_t bytes) -> void* {
        void* p = wsp + off;
        off = (off + bytes + 255) & ~(size_t)255;
        return p;
    };
    u16* x_bf   = (u16*)alloc((size_t)Mc * DIMc * 2);
    u16* Wq_b   = (u16*)alloc((size_t)DIMc * DIMc * 2);
    u16* Wk_b   = (u16*)alloc((size_t)256 * DIMc * 2);
    u16* Wv_b   = (u16*)alloc((size_t)256 * DIMc * 2);
    u16* Wo_b   = (u16*)alloc((size_t)DIMc * DIMc * 2);
    u16* AT_all = (u16*)alloc((size_t)96 * 1024 * 2);
    u16* pAT    = (u16*)alloc((size_t)32 * 1024 * 2);
    u16* qBT    = (u16*)alloc((size_t)1024 * 32 * 2);
    u16* kBT    = (u16*)alloc((size_t)256 * 32 * 2);
    u16* vBT    = (u16*)alloc((size_t)256 * 32 * 2);
    u16* pBT    = (u16*)alloc((size_t)1024 * 32 * 2);
    u16* xA     = (u16*)alloc((size_t)Mc * 96 * 2);
    u16* q_bf   = (u16*)alloc((size_t)Mc * DIMc * 2);
    u16* k_bf   = (u16*)alloc((size_t)Mc * 256 * 2);
    u16* v_bf   = (u16*)alloc((size_t)Mc * 256 * 2);
    u16* qatt   = (u16*)alloc((size_t)Mc * DIMc * 2);
    u16* katt   = (u16*)alloc((size_t)Mc * 256 * 2);
    u16* vatt   = (u16*)alloc((size_t)Mc * 256 * 2);
    u16* y_bf   = (u16*)alloc((size_t)Mc * DIMc * 2);
    u16* yA     = (u16*)alloc((size_t)Mc * 32 * 2);

    // prep
    transpose_small<<<dim3(128, 8), 256, 0, stream>>>(qA, kA, vA, pA, qB, kB, vB, pB,
                                                      AT_all, pAT, qBT, kBT, vBT, pBT);
    cast_f32_bf16<<<Mc * DIMc / 1024, 256, 0, stream>>>(x, x_bf);
    quant_rows<<<2560, 256, 0, stream>>>(Wq, Wk, Wv, Wo, Wq_b, Wk_b, Wv_b, Wo_b);

    // LoRA stage 1: xA = x @ [qA|kA|vA]  (M=4096, N=96, K=1024), bf16 out
    gemm64<<<dim3(2, 64), 256, 0, stream>>>(x_bf, DIMc, AT_all, 1024, 96, 1024,
                                            nullptr, 0, nullptr, 0,
                                            nullptr, nullptr, xA, nullptr, 96);
    // q = x @ Wq_deq^T + xA_q @ qB   (LoRA fused as K2=32 tail)
    gemm64<<<dim3(16, 64), 256, 0, stream>>>(x_bf, DIMc, Wq_b, DIMc, 1024, 1024,
                                             xA, 96, qBT, 32,
                                             nullptr, nullptr, q_bf, nullptr, DIMc);
    gemm64<<<dim3(4, 64), 256, 0, stream>>>(x_bf, DIMc, Wk_b, DIMc, 256, 1024,
                                            xA + 32, 96, kBT, 32,
                                            nullptr, nullptr, k_bf, nullptr, 256);
    gemm64<<<dim3(4, 64), 256, 0, stream>>>(x_bf, DIMc, Wv_b, DIMc, 256, 1024,
                                            xA + 64, 96, vBT, 32,
                                            nullptr, nullptr, v_bf, nullptr, 256);

    rope_pack<<<Mc, 256, 0, stream>>>(q_bf, k_bf, v_bf, q_gain, qatt, katt, vatt);
    flash_attn2<<<dim3(32, Bc * Hc), 256, 0, stream>>>(qatt, katt, vatt, head_gate, y_bf);

    // yA = y @ pA  (M=4096, N=32, K=1024)
    gemm64<<<dim3(1, 64), 256, 0, stream>>>(y_bf, DIMc, pAT, 1024, 32, 1024,
                                            nullptr, 0, nullptr, 0,
                                            nullptr, nullptr, yA, nullptr, 32);
    // out = y @ Wo_deq^T + yA @ pB
    gemm64<<<dim3(16, 64), 256, 0, stream>>>(y_bf, DIMc, Wo_b, DIMc, 1024, 1024,
                                             yA, 32, pBT, 32,
                                             out, nullptr, nullptr, nullptr, DIMc);
}

// Round 3
// 306.535 us; speedup vs baseline: 1.6112x; 1.2446x over previous
//
#include <hip/hip_runtime.h>
#include <hip/hip_fp16.h>

#define Bc   2
#define Tc   2048
#define DIMc 1024
#define Hc   16
#define KVHc 4
#define HDc  64
#define Mc   4096   // B*T

typedef unsigned short u16;
typedef __attribute__((ext_vector_type(8))) short short8;
typedef __attribute__((ext_vector_type(8))) __bf16 bf16x8;
typedef __attribute__((ext_vector_type(4))) float f32x4;
typedef __attribute__((ext_vector_type(4))) unsigned short u16x4;

typedef const __attribute__((address_space(1))) void* gas_t;
typedef __attribute__((address_space(3))) void* las_t;

__device__ inline float bf2f(u16 u) {
    unsigned int x = ((unsigned int)u) << 16;
    return __builtin_bit_cast(float, x);
}
__device__ inline u16 f2bf(float f) {  // RNE, no NaNs expected in this pipeline
    unsigned int x = __builtin_bit_cast(unsigned int, f);
    x += 0x7fffu + ((x >> 16) & 1u);
    return (u16)(x >> 16);
}
__device__ inline bf16x8 ld8(const u16* p) {
    return __builtin_bit_cast(bf16x8, *(const short8*)p);
}
__device__ inline f32x4 mfma16(bf16x8 a, bf16x8 b, f32x4 c) {
    return __builtin_amdgcn_mfma_f32_16x16x32_bf16(a, b, c, 0, 0, 0);
}
__device__ inline void gl_lds16(const u16* g, u16* l) {
    __builtin_amdgcn_global_load_lds((gas_t)g, (las_t)l, 16, 0, 0);
}

// ---------------------------------------------------------------------------
// Small transposes: LoRA matrices fp32 -> bf16 transposed (B^T operand layout)
// ---------------------------------------------------------------------------
__global__ __launch_bounds__(256) void transpose_small(
    const float* __restrict__ qA, const float* __restrict__ kA,
    const float* __restrict__ vA, const float* __restrict__ pA,
    const float* __restrict__ qB, const float* __restrict__ kB,
    const float* __restrict__ vB, const float* __restrict__ pB,
    u16* __restrict__ AT_all, u16* __restrict__ pAT,
    u16* __restrict__ qBT, u16* __restrict__ kBT,
    u16* __restrict__ vBT, u16* __restrict__ pBT)
{
    const int seg = blockIdx.y;
    const float* src; u16* dst; int R, C;
    switch (seg) {
        case 0: src = qA; dst = AT_all;             R = 1024; C = 32;  break;
        case 1: src = kA; dst = AT_all + 32 * 1024; R = 1024; C = 32;  break;
        case 2: src = vA; dst = AT_all + 64 * 1024; R = 1024; C = 32;  break;
        case 3: src = pA; dst = pAT;                R = 1024; C = 32;  break;
        case 4: src = qB; dst = qBT;                R = 32; C = 1024;  break;
        case 5: src = kB; dst = kBT;                R = 32; C = 256;   break;
        case 6: src = vB; dst = vBT;                R = 32; C = 256;   break;
        default: src = pB; dst = pBT;               R = 32; C = 1024;  break;
    }
    const int idx = blockIdx.x * 256 + threadIdx.x;
    if (idx < R * C) {
        const int r = idx / C, c = idx % C;
        dst[(size_t)c * R + r] = f2bf(src[(size_t)r * C + c]);
    }
}

// ---------------------------------------------------------------------------
__global__ __launch_bounds__(256) void cast_f32_bf16(
    const float* __restrict__ src, u16* __restrict__ dst)
{
    const int i = blockIdx.x * 256 + threadIdx.x;
    float4 v = ((const float4*)src)[i];
    u16x4 o = {f2bf(v.x), f2bf(v.y), f2bf(v.z), f2bf(v.w)};
    ((u16x4*)dst)[i] = o;
}

// ---------------------------------------------------------------------------
// Per-row int6 RTN fake-quant with clip-candidate search. One block per row.
// ---------------------------------------------------------------------------
__device__ inline float block_sum(float v, volatile float* red) {
    #pragma unroll
    for (int off = 32; off; off >>= 1) v += __shfl_xor(v, off);
    __syncthreads();
    if ((threadIdx.x & 63) == 0) red[threadIdx.x >> 6] = v;
    __syncthreads();
    return red[0] + red[1] + red[2] + red[3];
}
__device__ inline float block_max(float v, volatile float* red) {
    #pragma unroll
    for (int off = 32; off; off >>= 1) v = fmaxf(v, __shfl_xor(v, off));
    __syncthreads();
    if ((threadIdx.x & 63) == 0) red[threadIdx.x >> 6] = v;
    __syncthreads();
    return fmaxf(fmaxf(red[0], red[1]), fmaxf(red[2], red[3]));
}

__global__ __launch_bounds__(256) void quant_rows(
    const float* __restrict__ Wq, const float* __restrict__ Wk,
    const float* __restrict__ Wv, const float* __restrict__ Wo,
    u16* __restrict__ Wqb, u16* __restrict__ Wkb,
    u16* __restrict__ Wvb, u16* __restrict__ Wob)
{
    __shared__ float red[4];
    const int rblk = blockIdx.x;
    const float* src; u16* dst; int rr;
    if (rblk < 1024)      { src = Wq; dst = Wqb; rr = rblk; }
    else if (rblk < 1280) { src = Wk; dst = Wkb; rr = rblk - 1024; }
    else if (rblk < 1536) { src = Wv; dst = Wvb; rr = rblk - 1280; }
    else                  { src = Wo; dst = Wob; rr = rblk - 1536; }
    src += (size_t)rr * DIMc;
    dst += (size_t)rr * DIMc;
    const int tid = threadIdx.x;

    float4 fv = ((const float4*)src)[tid];          // 256 thr x 4 = 1024 cols
    float tv[4] = {fv.x, fv.y, fv.z, fv.w};
    float ps = tv[0] + tv[1] + tv[2] + tv[3];
    float pa = fmaxf(fmaxf(fabsf(tv[0]), fabsf(tv[1])),
                     fmaxf(fabsf(tv[2]), fabsf(tv[3])));
    const float sum  = block_sum(ps, red);
    const float amax = block_max(pa, red);
    const float mean = sum * (1.0f / 1024.0f);
    float psq = 0.f;
    #pragma unroll
    for (int j = 0; j < 4; j++) { float d = tv[j] - mean; psq += d * d; }
    const float var  = block_sum(psq, red) * (1.0f / 1024.0f);
    const float row_std    = fmaxf(sqrtf(var), 1e-8f);
    const float row_absmax = fmaxf(amax, 1.0f / 31.0f);
    const float s1 = fmaxf(fmaxf(row_std * 12.85f, row_absmax * (1.0f / 31.0f)) * (1.0f / 31.0f),
                           1.0f / 31.0f);
    const float s2 = fmaxf(row_absmax * (1.0f / 31.0f), 1.0f / 31.0f);
    float pe1 = 0.f, pe2 = 0.f;
    #pragma unroll
    for (int j = 0; j < 4; j++) {
        float q1 = fminf(fmaxf(rintf(tv[j] / s1), -31.f), 31.f);
        float q2 = fminf(fmaxf(rintf(tv[j] / s2), -31.f), 31.f);
        float d1 = q1 * s1 - tv[j], d2 = q2 * s2 - tv[j];
        pe1 += d1 * d1; pe2 += d2 * d2;
    }
    const float e1 = block_sum(pe1, red);
    const float e2 = block_sum(pe2, red);
    const float ss = (e1 < e2) ? s1 : s2;
    const float sh = __half2float(__float2half(ss));  // fp16 round-trip of scale
    u16x4 outv;
    #pragma unroll
    for (int j = 0; j < 4; j++) {
        float q = fminf(fmaxf(rintf(tv[j] / ss), -31.f), 31.f);
        outv[j] = f2bf(q * sh);
    }
    ((u16x4*)dst)[tid] = outv;
}

// ---------------------------------------------------------------------------
// Generic bf16 MFMA GEMM: C[M,N] = A[M,K] @ B[N,K]^T (+ optional fused second
// K=32 LoRA segment) (+ optional add-input). 64x64 tile, 4 waves.
// ---------------------------------------------------------------------------
__global__ __launch_bounds__(256) void gemm64(
    const u16* __restrict__ A, int lda,
    const u16* __restrict__ Bm, int ldb,
    int N, int K,
    const u16* __restrict__ A2, int lda2,
    const u16* __restrict__ B2, int ldb2,
    float* __restrict__ Cf, const float* __restrict__ Caddf,
    u16* __restrict__ Cb, const u16* __restrict__ Caddb, int ldc)
{
    __shared__ __align__(16) u16 As[64 * 40];
    __shared__ __align__(16) u16 Bs[64 * 40];
    const int tid  = threadIdx.x;
    const int wave = tid >> 6, lane = tid & 63;
    const int quad = lane >> 4, l16 = lane & 15;
    const int wm = wave >> 1, wn = wave & 1;
    const int tileM = blockIdx.y * 64;
    const int tileN = blockIdx.x * 64;
    const int lrow = tid >> 2;        // 0..63
    const int lcol = (tid & 3) * 8;   // 0,8,16,24

    f32x4 acc[2][2] = {};
    const u16* Aptr = A + (size_t)(tileM + lrow) * lda + lcol;
    const u16* Bptr = Bm + (size_t)(tileN + lrow) * ldb + lcol;
    const bool bvalid = (tileN + lrow) < N;

    for (int k0 = 0; k0 < K; k0 += 32) {
        __syncthreads();
        short8 av = *(const short8*)(Aptr + k0);
        short8 bv = {};
        if (bvalid) bv = *(const short8*)(Bptr + k0);
        *(short8*)&As[lrow * 40 + lcol] = av;
        *(short8*)&Bs[lrow * 40 + lcol] = bv;
        __syncthreads();
        bf16x8 a0 = ld8(&As[(wm * 32 + l16) * 40 + quad * 8]);
        bf16x8 a1 = ld8(&As[(wm * 32 + 16 + l16) * 40 + quad * 8]);
        bf16x8 b0 = ld8(&Bs[(wn * 32 + l16) * 40 + quad * 8]);
        bf16x8 b1 = ld8(&Bs[(wn * 32 + 16 + l16) * 40 + quad * 8]);
        acc[0][0] = mfma16(a0, b0, acc[0][0]);
        acc[0][1] = mfma16(a0, b1, acc[0][1]);
        acc[1][0] = mfma16(a1, b0, acc[1][0]);
        acc[1][1] = mfma16(a1, b1, acc[1][1]);
    }
    if (A2) {  // fused LoRA K=32 segment
        __syncthreads();
        short8 av = *(const short8*)(A2 + (size_t)(tileM + lrow) * lda2 + lcol);
        short8 bv = {};
        if (bvalid) bv = *(const short8*)(B2 + (size_t)(tileN + lrow) * ldb2 + lcol);
        *(short8*)&As[lrow * 40 + lcol] = av;
        *(short8*)&Bs[lrow * 40 + lcol] = bv;
        __syncthreads();
        bf16x8 a0 = ld8(&As[(wm * 32 + l16) * 40 + quad * 8]);
        bf16x8 a1 = ld8(&As[(wm * 32 + 16 + l16) * 40 + quad * 8]);
        bf16x8 b0 = ld8(&Bs[(wn * 32 + l16) * 40 + quad * 8]);
        bf16x8 b1 = ld8(&Bs[(wn * 32 + 16 + l16) * 40 + quad * 8]);
        acc[0][0] = mfma16(a0, b0, acc[0][0]);
        acc[0][1] = mfma16(a0, b1, acc[0][1]);
        acc[1][0] = mfma16(a1, b0, acc[1][0]);
        acc[1][1] = mfma16(a1, b1, acc[1][1]);
    }
    #pragma unroll
    for (int mi = 0; mi < 2; mi++)
    #pragma unroll
    for (int ni = 0; ni < 2; ni++)
    #pragma unroll
    for (int r = 0; r < 4; r++) {
        const int row = tileM + wm * 32 + mi * 16 + quad * 4 + r;
        const int col = tileN + wn * 32 + ni * 16 + l16;
        if (col < N) {
            float v = acc[mi][ni][r];
            const size_t idx = (size_t)row * ldc + col;
            if (Caddf) v += Caddf[idx];
            if (Caddb) v += bf2f(Caddb[idx]);
            if (Cf) Cf[idx] = v;
            if (Cb) Cb[idx] = f2bf(v);
        }
    }
}

// ---------------------------------------------------------------------------
// RoPE + repack (unchanged from round 2).
// ---------------------------------------------------------------------------
__global__ __launch_bounds__(256) void rope_pack(
    const u16* __restrict__ qin, const u16* __restrict__ kin,
    const u16* __restrict__ vin, const float* __restrict__ q_gain,
    u16* __restrict__ qatt, u16* __restrict__ katt, u16* __restrict__ vatt)
{
    const int i = blockIdx.x;             // b*T + t
    const int b = i >> 11, t = i & (Tc - 1);
    const int tid = threadIdx.x;
    const float L2B = 0.41524101186092035f;   // log2(10000)/32

    for (int pi = tid; pi < Hc * 32; pi += 256) {
        const int h = pi >> 5, p = pi & 31;
        const float x1 = bf2f(qin[(size_t)i * DIMc + h * HDc + p]);
        const float x2 = bf2f(qin[(size_t)i * DIMc + h * HDc + 32 + p]);
        const float fr = (float)t * exp2f(-L2B * (float)p);
        float s, c; sincosf(fr, &s, &c);
        const float g = q_gain[h] * 0.125f;   // fold 1/sqrt(HD) into q
        const size_t o = ((size_t)(b * Hc + h) * Tc + t) * HDc + p;
        qatt[o]      = f2bf((x1 * c + x2 * s) * g);
        qatt[o + 32] = f2bf((x2 * c - x1 * s) * g);
    }
    for (int pi = tid; pi < KVHc * 32; pi += 256) {
        const int kh = pi >> 5, p = pi & 31;
        const float x1 = bf2f(kin[(size_t)i * (KVHc * HDc) + kh * HDc + p]);
        const float x2 = bf2f(kin[(size_t)i * (KVHc * HDc) + kh * HDc + 32 + p]);
        const float fr = (float)t * exp2f(-L2B * (float)p);
        float s, c; sincosf(fr, &s, &c);
        const size_t o = ((size_t)(b * KVHc + kh) * Tc + t) * HDc + p;
        katt[o]      = f2bf(x1 * c + x2 * s);
        katt[o + 32] = f2bf(x2 * c - x1 * s);
    }
    for (int e = tid; e < KVHc * HDc; e += 256) {
        const int kh = e >> 6, hd = e & 63;
        vatt[((size_t)(b * KVHc + kh) * HDc + hd) * Tc + t] =
            vin[(size_t)i * (KVHc * HDc) + e];
    }
}

// ---------------------------------------------------------------------------
// Flash attention v3. Block = 4 waves owning 64 CONSECUTIVE q rows (16/wave),
// so all waves share the K/V tile sequence. K(64x64) and V^T(64x64) tiles are
// staged into double-buffered LDS via global_load_lds width=16 (coalesced,
// 4x amortized, prefetched one tile ahead; single barrier per iteration).
// XOR swizzle (chunk ^= row&7) applied on the GLOBAL address side of the DMA
// so the pad-free LDS layout still yields floor-rate ds_read_b128 frag reads.
// S^T = K @ Q^T; softmax per-lane (col=q) with 2 shfl_xor; O^T = V @ P^T.
// LDS: 2*8K (K) + 2*8K (V) + 4*2K (P) = 40 KB -> 4 blocks/CU, 16 waves/CU.
// ---------------------------------------------------------------------------
__global__ __launch_bounds__(256) void flash_attn3(
    const u16* __restrict__ qatt, const u16* __restrict__ katt,
    const u16* __restrict__ vatt, const float* __restrict__ head_gate,
    u16* __restrict__ ybf)
{
    __shared__ __align__(16) u16 sm[20480];   // [0,8192)=Kdbuf [8192,16384)=Vdbuf [16384,20480)=P
    const int tid = threadIdx.x;
    const int wv = tid >> 6, lane = tid & 63;
    const int quad = lane >> 4, l16 = lane & 15;
    const int sw = l16 & 7;
    const int bh = blockIdx.y;
    const int b = bh >> 4, h = bh & 15;
    const int kvh = h >> 2;
    const int qtile = (bh & 1) ? (31 - (int)blockIdx.x) : (int)blockIdx.x;
    const int qb = qtile * 64;
    const int qw = qb + wv * 16;               // this wave's 16 q rows
    const int nkt = qtile + 1;                 // 64-key tiles up to diagonal

    const u16* qbase = qatt + ((size_t)((b * Hc + h) * Tc + qw + l16)) * HDc;
    const bf16x8 bq0 = ld8(qbase + quad * 8);        // B-frag: n=q, k=d 0..31
    const bf16x8 bq1 = ld8(qbase + 32 + quad * 8);

    const u16* kbase = katt + (size_t)(b * KVHc + kvh) * Tc * HDc;
    const u16* vbase = vatt + (size_t)(b * KVHc + kvh) * HDc * Tc;

    // stage one 64x64 tile pair into LDS buffer bb (all 4 waves participate).
    // linear chunk g = wv*128 + i*64 + lane; row r=g>>3; LDS chunk cs=g&7 holds
    // global chunk cg = cs ^ (r&7).
    auto stage = [&](int k0, int bb) {
        #pragma unroll
        for (int i = 0; i < 2; i++) {
            const int g = wv * 128 + i * 64 + lane;
            const int r = g >> 3;
            const int cg = (g & 7) ^ (r & 7);
            gl_lds16(kbase + (size_t)(k0 + r) * HDc + cg * 8,
                     &sm[bb * 4096 + wv * 1024 + i * 512]);
            gl_lds16(vbase + (size_t)r * Tc + k0 + cg * 8,
                     &sm[8192 + bb * 4096 + wv * 1024 + i * 512]);
        }
    };

    float m_run = -3.0e38f, l_run = 0.f;
    f32x4 o[4] = {};                    // O^T: col=q(l16), row=hd f*16+quad*4+r
    u16* pw = &sm[16384 + wv * 1024];   // wave-private P: 16 rows x 128B, swizzled

    stage(0, 0);
    for (int kt = 0; kt < nkt; kt++) {
        const int bb = kt & 1;
        __syncthreads();                         // drains stage(kt) (vmcnt 0)
        if (kt + 1 < nkt) stage((kt + 1) * 64, bb ^ 1);

        const u16* Kb = &sm[bb * 4096];
        const u16* Vb = &sm[8192 + bb * 4096];
        f32x4 st[4];
        #pragma unroll
        for (int ft = 0; ft < 4; ft++) {
            const u16* kp = Kb + (ft * 16 + l16) * 64;
            bf16x8 a0 = ld8(kp + ((quad ^ sw) << 3));         // d 0..31
            bf16x8 a1 = ld8(kp + (((quad + 4) ^ sw) << 3));   // d 32..63
            f32x4 s = {};
            s = mfma16(a0, bq0, s);
            s = mfma16(a1, bq1, s);
            st[ft] = s;               // col=q(l16), local key=ft*16+quad*4+r
        }
        if (kt == nkt - 1) {          // diagonal tile: causal mask (local idx)
            const int qloc = wv * 16 + l16;
            #pragma unroll
            for (int ft = 0; ft < 4; ft++)
                #pragma unroll
                for (int r = 0; r < 4; r++)
                    if (ft * 16 + quad * 4 + r > qloc) st[ft][r] = -1e30f;
        }
        // per-q max: in-register tree + 2 cross-quad shuffles
        float vm = fmaxf(fmaxf(st[0][0], st[0][1]), fmaxf(st[0][2], st[0][3]));
        #pragma unroll
        for (int ft = 1; ft < 4; ft++)
            vm = fmaxf(vm, fmaxf(fmaxf(st[ft][0], st[ft][1]),
                                 fmaxf(st[ft][2], st[ft][3])));
        vm = fmaxf(vm, __shfl_xor(vm, 16));
        vm = fmaxf(vm, __shfl_xor(vm, 32));
        const float mnew = fmaxf(m_run, vm);
        const float alpha = __expf(m_run - mnew);
        m_run = mnew;

        float psum = 0.f;
        #pragma unroll
        for (int ft = 0; ft < 4; ft++) {
            float p0 = __expf(st[ft][0] - mnew);
            float p1 = __expf(st[ft][1] - mnew);
            float p2 = __expf(st[ft][2] - mnew);
            float p3 = __expf(st[ft][3] - mnew);
            psum += (p0 + p1) + (p2 + p3);
            u16x4 pk = {f2bf(p0), f2bf(p1), f2bf(p2), f2bf(p3)};
            const int c = (ft << 1) + (quad >> 1);            // 16B chunk idx
            *(u16x4*)&pw[(l16 << 6) + ((c ^ sw) << 3) + ((quad & 1) << 2)] = pk;
        }
        psum += __shfl_xor(psum, 16);
        psum += __shfl_xor(psum, 32);
        l_run = l_run * alpha + psum;

        #pragma unroll
        for (int f = 0; f < 4; f++) {
            o[f][0] *= alpha; o[f][1] *= alpha;
            o[f][2] *= alpha; o[f][3] *= alpha;
        }
        // P back as B-frag: n=q(l16), k=key (swizzled chunks)
        const bf16x8 pa0 = ld8(&pw[(l16 << 6) + ((quad ^ sw) << 3)]);
        const bf16x8 pa1 = ld8(&pw[(l16 << 6) + (((quad + 4) ^ sw) << 3)]);
        #pragma unroll
        for (int f = 0; f < 4; f++) {
            const u16* vp = Vb + (f * 16 + l16) * 64;
            bf16x8 v0 = ld8(vp + ((quad ^ sw) << 3));         // keys 0..31
            bf16x8 v1 = ld8(vp + (((quad + 4) ^ sw) << 3));   // keys 32..63
            o[f] = mfma16(v0, pa0, o[f]);     // O^T += V * P^T
            o[f] = mfma16(v1, pa1, o[f]);
        }
    }
    const float inv = head_gate[h] / l_run;       // per-q, in-lane (q = l16)
    u16* yb = ybf + ((size_t)(b * Tc + qw + l16)) * DIMc + h * HDc + quad * 4;
    #pragma unroll
    for (int f = 0; f < 4; f++) {
        u16x4 pk = {f2bf(o[f][0] * inv), f2bf(o[f][1] * inv),
                    f2bf(o[f][2] * inv), f2bf(o[f][3] * inv)};
        *(u16x4*)(yb + f * 16) = pk;
    }
}

// ---------------------------------------------------------------------------
extern "C" void kernel_launch(void* const* d_in, const int* in_sizes, int n_in,
                              void* d_out, int out_size, void* d_ws, size_t ws_size,
                              hipStream_t stream) {
    (void)in_sizes; (void)n_in; (void)out_size; (void)ws_size;
    const float* x    = (const float*)d_in[0];
    const float* Wq   = (const float*)d_in[1];
    const float* Wk   = (const float*)d_in[2];
    const float* Wv   = (const float*)d_in[3];
    const float* Wo   = (const float*)d_in[4];
    const float* qA   = (const float*)d_in[5];
    const float* qB   = (const float*)d_in[6];
    const float* kA   = (const float*)d_in[7];
    const float* kB   = (const float*)d_in[8];
    const float* vA   = (const float*)d_in[9];
    const float* vB   = (const float*)d_in[10];
    const float* pA   = (const float*)d_in[11];
    const float* pB   = (const float*)d_in[12];
    const float* q_gain    = (const float*)d_in[13];
    const float* head_gate = (const float*)d_in[14];
    float* out = (float*)d_out;

    char* wsp = (char*)d_ws;
    size_t off = 0;
    auto alloc = [&](size_t bytes) -> void* {
        void* p = wsp + off;
        off = (off + bytes + 255) & ~(size_t)255;
        return p;
    };
    u16* x_bf   = (u16*)alloc((size_t)Mc * DIMc * 2);
    u16* Wq_b   = (u16*)alloc((size_t)DIMc * DIMc * 2);
    u16* Wk_b   = (u16*)alloc((size_t)256 * DIMc * 2);
    u16* Wv_b   = (u16*)alloc((size_t)256 * DIMc * 2);
    u16* Wo_b   = (u16*)alloc((size_t)DIMc * DIMc * 2);
    u16* AT_all = (u16*)alloc((size_t)96 * 1024 * 2);
    u16* pAT    = (u16*)alloc((size_t)32 * 1024 * 2);
    u16* qBT    = (u16*)alloc((size_t)1024 * 32 * 2);
    u16* kBT    = (u16*)alloc((size_t)256 * 32 * 2);
    u16* vBT    = (u16*)alloc((size_t)256 * 32 * 2);
    u16* pBT    = (u16*)alloc((size_t)1024 * 32 * 2);
    u16* xA     = (u16*)alloc((size_t)Mc * 96 * 2);
    u16* q_bf   = (u16*)alloc((size_t)Mc * DIMc * 2);
    u16* k_bf   = (u16*)alloc((size_t)Mc * 256 * 2);
    u16* v_bf   = (u16*)alloc((size_t)Mc * 256 * 2);
    u16* qatt   = (u16*)alloc((size_t)Mc * DIMc * 2);
    u16* katt   = (u16*)alloc((size_t)Mc * 256 * 2);
    u16* vatt   = (u16*)alloc((size_t)Mc * 256 * 2);
    u16* y_bf   = (u16*)alloc((size_t)Mc * DIMc * 2);
    u16* yA     = (u16*)alloc((size_t)Mc * 32 * 2);

    // prep
    transpose_small<<<dim3(128, 8), 256, 0, stream>>>(qA, kA, vA, pA, qB, kB, vB, pB,
                                                      AT_all, pAT, qBT, kBT, vBT, pBT);
    cast_f32_bf16<<<Mc * DIMc / 1024, 256, 0, stream>>>(x, x_bf);
    quant_rows<<<2560, 256, 0, stream>>>(Wq, Wk, Wv, Wo, Wq_b, Wk_b, Wv_b, Wo_b);

    // LoRA stage 1: xA = x @ [qA|kA|vA]  (M=4096, N=96, K=1024), bf16 out
    gemm64<<<dim3(2, 64), 256, 0, stream>>>(x_bf, DIMc, AT_all, 1024, 96, 1024,
                                            nullptr, 0, nullptr, 0,
                                            nullptr, nullptr, xA, nullptr, 96);
    // q = x @ Wq_deq^T + xA_q @ qB   (LoRA fused as K2=32 tail)
    gemm64<<<dim3(16, 64), 256, 0, stream>>>(x_bf, DIMc, Wq_b, DIMc, 1024, 1024,
                                             xA, 96, qBT, 32,
                                             nullptr, nullptr, q_bf, nullptr, DIMc);
    gemm64<<<dim3(4, 64), 256, 0, stream>>>(x_bf, DIMc, Wk_b, DIMc, 256, 1024,
                                            xA + 32, 96, kBT, 32,
                                            nullptr, nullptr, k_bf, nullptr, 256);
    gemm64<<<dim3(4, 64), 256, 0, stream>>>(x_bf, DIMc, Wv_b, DIMc, 256, 1024,
                                            xA + 64, 96, vBT, 32,
                                            nullptr, nullptr, v_bf, nullptr, 256);

    rope_pack<<<Mc, 256, 0, stream>>>(q_bf, k_bf, v_bf, q_gain, qatt, katt, vatt);
    flash_attn3<<<dim3(32, Bc * Hc), 256, 0, stream>>>(qatt, katt, vatt, head_gate, y_bf);

    // yA = y @ pA  (M=4096, N=32, K=1024)
    gemm64<<<dim3(1, 64), 256, 0, stream>>>(y_bf, DIMc, pAT, 1024, 32, 1024,
                                            nullptr, 0, nullptr, 0,
                                            nullptr, nullptr, yA, nullptr, 32);
    // out = y @ Wo_deq^T + yA @ pB
    gemm64<<<dim3(16, 64), 256, 0, stream>>>(y_bf, DIMc, Wo_b, DIMc, 1024, 1024,
                                             yA, 32, pBT, 32,
                                             out, nullptr, nullptr, nullptr, DIMc);
}

// Round 4
// 301.947 us; speedup vs baseline: 1.6357x; 1.0152x over previous
//
#include <hip/hip_runtime.h>
#include <hip/hip_fp16.h>

#define Bc   2
#define Tc   2048
#define DIMc 1024
#define Hc   16
#define KVHc 4
#define HDc  64
#define Mc   4096   // B*T

typedef unsigned short u16;
typedef __attribute__((ext_vector_type(8))) short short8;
typedef __attribute__((ext_vector_type(8))) __bf16 bf16x8;
typedef __attribute__((ext_vector_type(4))) float f32x4;
typedef __attribute__((ext_vector_type(4))) unsigned short u16x4;

typedef const __attribute__((address_space(1))) void* gas_t;
typedef __attribute__((address_space(3))) void* las_t;

__device__ inline float bf2f(u16 u) {
    unsigned int x = ((unsigned int)u) << 16;
    return __builtin_bit_cast(float, x);
}
__device__ inline u16 f2bf(float f) {  // RNE
    unsigned int x = __builtin_bit_cast(unsigned int, f);
    x += 0x7fffu + ((x >> 16) & 1u);
    return (u16)(x >> 16);
}
__device__ inline bf16x8 ld8(const u16* p) {
    return __builtin_bit_cast(bf16x8, *(const short8*)p);
}
__device__ inline f32x4 mfma16(bf16x8 a, bf16x8 b, f32x4 c) {
    return __builtin_amdgcn_mfma_f32_16x16x32_bf16(a, b, c, 0, 0, 0);
}
__device__ inline void gl_lds16(const u16* g, u16* l) {
    __builtin_amdgcn_global_load_lds((gas_t)g, (las_t)l, 16, 0, 0);
}

// ---------------------------------------------------------------------------
// prep: blocks [0,1024) transposes, [1024,5120) x cast, [5120,7680) quant.
// ---------------------------------------------------------------------------
__device__ inline float block_sum(float v, volatile float* red) {
    #pragma unroll
    for (int off = 32; off; off >>= 1) v += __shfl_xor(v, off);
    __syncthreads();
    if ((threadIdx.x & 63) == 0) red[threadIdx.x >> 6] = v;
    __syncthreads();
    return red[0] + red[1] + red[2] + red[3];
}
__device__ inline float block_max(float v, volatile float* red) {
    #pragma unroll
    for (int off = 32; off; off >>= 1) v = fmaxf(v, __shfl_xor(v, off));
    __syncthreads();
    if ((threadIdx.x & 63) == 0) red[threadIdx.x >> 6] = v;
    __syncthreads();
    return fmaxf(fmaxf(red[0], red[1]), fmaxf(red[2], red[3]));
}

__global__ __launch_bounds__(256) void prep_kernel(
    const float* __restrict__ x,
    const float* __restrict__ Wq, const float* __restrict__ Wk,
    const float* __restrict__ Wv, const float* __restrict__ Wo,
    const float* __restrict__ qA, const float* __restrict__ kA,
    const float* __restrict__ vA, const float* __restrict__ pA,
    const float* __restrict__ qB, const float* __restrict__ kB,
    const float* __restrict__ vB, const float* __restrict__ pB,
    u16* __restrict__ x_bf,
    u16* __restrict__ Wq_b, u16* __restrict__ Wkv_b, u16* __restrict__ Wo_b,
    u16* __restrict__ AT_all, u16* __restrict__ pAT,
    u16* __restrict__ qBT, u16* __restrict__ kvBT, u16* __restrict__ pBT)
{
    __shared__ float red[4];
    const int bx = blockIdx.x;
    const int tid = threadIdx.x;

    if (bx < 1024) {                       // --- small transposes ---
        const int seg = bx >> 7;
        const float* src; u16* dst; int R, C;
        switch (seg) {
            case 0: src = qA; dst = AT_all;             R = 1024; C = 32;  break;
            case 1: src = kA; dst = AT_all + 32 * 1024; R = 1024; C = 32;  break;
            case 2: src = vA; dst = AT_all + 64 * 1024; R = 1024; C = 32;  break;
            case 3: src = pA; dst = pAT;                R = 1024; C = 32;  break;
            case 4: src = qB; dst = qBT;                R = 32; C = 1024;  break;
            case 5: src = kB; dst = kvBT;               R = 32; C = 256;   break;
            case 6: src = vB; dst = kvBT + 256 * 32;    R = 32; C = 256;   break;
            default: src = pB; dst = pBT;               R = 32; C = 1024;  break;
        }
        const int idx = (bx & 127) * 256 + tid;
        if (idx < R * C) {
            const int r = idx / C, c = idx % C;
            dst[(size_t)c * R + r] = f2bf(src[(size_t)r * C + c]);
        }
        return;
    }
    if (bx < 5120) {                       // --- x fp32 -> bf16 ---
        const int i = (bx - 1024) * 256 + tid;
        float4 v = ((const float4*)x)[i];
        u16x4 o = {f2bf(v.x), f2bf(v.y), f2bf(v.z), f2bf(v.w)};
        ((u16x4*)x_bf)[i] = o;
        return;
    }
    // --- int6 RTN fake-quant, one block per weight row ---
    const int rblk = bx - 5120;
    const float* src; u16* dst;
    if (rblk < 1024)      { src = Wq + (size_t)rblk * DIMc;          dst = Wq_b + (size_t)rblk * DIMc; }
    else if (rblk < 1280) { src = Wk + (size_t)(rblk - 1024) * DIMc; dst = Wkv_b + (size_t)(rblk - 1024) * DIMc; }
    else if (rblk < 1536) { src = Wv + (size_t)(rblk - 1280) * DIMc; dst = Wkv_b + (size_t)(rblk - 1024) * DIMc; }
    else                  { src = Wo + (size_t)(rblk - 1536) * DIMc; dst = Wo_b + (size_t)(rblk - 1536) * DIMc; }

    float4 fv = ((const float4*)src)[tid];
    float tv[4] = {fv.x, fv.y, fv.z, fv.w};
    float ps = tv[0] + tv[1] + tv[2] + tv[3];
    float pa = fmaxf(fmaxf(fabsf(tv[0]), fabsf(tv[1])),
                     fmaxf(fabsf(tv[2]), fabsf(tv[3])));
    const float sum  = block_sum(ps, red);
    const float amax = block_max(pa, red);
    const float mean = sum * (1.0f / 1024.0f);
    float psq = 0.f;
    #pragma unroll
    for (int j = 0; j < 4; j++) { float d = tv[j] - mean; psq += d * d; }
    const float var  = block_sum(psq, red) * (1.0f / 1024.0f);
    const float row_std    = fmaxf(sqrtf(var), 1e-8f);
    const float row_absmax = fmaxf(amax, 1.0f / 31.0f);
    const float s1 = fmaxf(fmaxf(row_std * 12.85f, row_absmax * (1.0f / 31.0f)) * (1.0f / 31.0f),
                           1.0f / 31.0f);
    const float s2 = fmaxf(row_absmax * (1.0f / 31.0f), 1.0f / 31.0f);
    float pe1 = 0.f, pe2 = 0.f;
    #pragma unroll
    for (int j = 0; j < 4; j++) {
        float q1 = fminf(fmaxf(rintf(tv[j] / s1), -31.f), 31.f);
        float q2 = fminf(fmaxf(rintf(tv[j] / s2), -31.f), 31.f);
        float d1 = q1 * s1 - tv[j], d2 = q2 * s2 - tv[j];
        pe1 += d1 * d1; pe2 += d2 * d2;
    }
    const float e1 = block_sum(pe1, red);
    const float e2 = block_sum(pe2, red);
    const float ss = (e1 < e2) ? s1 : s2;
    const float sh = __half2float(__float2half(ss));
    u16x4 outv;
    #pragma unroll
    for (int j = 0; j < 4; j++) {
        float q = fminf(fmaxf(rintf(tv[j] / ss), -31.f), 31.f);
        outv[j] = f2bf(q * sh);
    }
    ((u16x4*)dst)[tid] = outv;
}

// ---------------------------------------------------------------------------
// gemm64: C[M,N] = A[M,K] @ B[N,K]^T, bf16 out. Small-N helper (N guarded).
// ---------------------------------------------------------------------------
__global__ __launch_bounds__(256) void gemm64(
    const u16* __restrict__ A, int lda,
    const u16* __restrict__ Bm, int ldb,
    int N, int K, u16* __restrict__ Cb, int ldc)
{
    __shared__ __align__(16) u16 As[64 * 40];
    __shared__ __align__(16) u16 Bs[64 * 40];
    const int tid  = threadIdx.x;
    const int wave = tid >> 6, lane = tid & 63;
    const int quad = lane >> 4, l16 = lane & 15;
    const int wm = wave >> 1, wn = wave & 1;
    const int tileM = blockIdx.y * 64;
    const int tileN = blockIdx.x * 64;
    const int lrow = tid >> 2;
    const int lcol = (tid & 3) * 8;

    f32x4 acc[2][2] = {};
    const u16* Aptr = A + (size_t)(tileM + lrow) * lda + lcol;
    const u16* Bptr = Bm + (size_t)(tileN + lrow) * ldb + lcol;
    const bool bvalid = (tileN + lrow) < N;

    for (int k0 = 0; k0 < K; k0 += 32) {
        __syncthreads();
        short8 av = *(const short8*)(Aptr + k0);
        short8 bv = {};
        if (bvalid) bv = *(const short8*)(Bptr + k0);
        *(short8*)&As[lrow * 40 + lcol] = av;
        *(short8*)&Bs[lrow * 40 + lcol] = bv;
        __syncthreads();
        bf16x8 a0 = ld8(&As[(wm * 32 + l16) * 40 + quad * 8]);
        bf16x8 a1 = ld8(&As[(wm * 32 + 16 + l16) * 40 + quad * 8]);
        bf16x8 b0 = ld8(&Bs[(wn * 32 + l16) * 40 + quad * 8]);
        bf16x8 b1 = ld8(&Bs[(wn * 32 + 16 + l16) * 40 + quad * 8]);
        acc[0][0] = mfma16(a0, b0, acc[0][0]);
        acc[0][1] = mfma16(a0, b1, acc[0][1]);
        acc[1][0] = mfma16(a1, b0, acc[1][0]);
        acc[1][1] = mfma16(a1, b1, acc[1][1]);
    }
    #pragma unroll
    for (int mi = 0; mi < 2; mi++)
    #pragma unroll
    for (int ni = 0; ni < 2; ni++)
    #pragma unroll
    for (int r = 0; r < 4; r++) {
        const int row = tileM + wm * 32 + mi * 16 + quad * 4 + r;
        const int col = tileN + wn * 32 + ni * 16 + l16;
        if (col < N)
            Cb[(size_t)row * ldc + col] = f2bf(acc[mi][ni][r]);
    }
}

// ---------------------------------------------------------------------------
// gemm128 (m97-style): C[M,N] = A[M,K] @ B[N,K]^T (+ K2=32 LoRA tail).
// 128x128 tile, 4 waves each 64x64 (4x4 f32x4 acc). BK=32.
// Staging via global_load_lds w=16 into pad-free LDS; double-XOR chunk
// swizzle (c ^ r&3 ^ (r>>2)&3) applied on the GLOBAL side so frag
// ds_read_b128 lands 2-way max. 2-barrier K-loop. M,N multiples of 128.
// A2 select: tileN >= a2split ? A2b : A2a (for the fused kv projection).
// ---------------------------------------------------------------------------
__global__ __launch_bounds__(256) void gemm128(
    const u16* __restrict__ A, int lda,
    const u16* __restrict__ Bm, int ldb, int K,
    const u16* __restrict__ A2a, const u16* __restrict__ A2b,
    int a2split, int lda2,
    const u16* __restrict__ B2, int ldb2,
    float* __restrict__ Cf, u16* __restrict__ Cb, int ldc)
{
    __shared__ __align__(16) u16 As[128 * 32];
    __shared__ __align__(16) u16 Bs[128 * 32];
    const int tid = threadIdx.x;
    const int wave = tid >> 6, lane = tid & 63;
    const int quad = lane >> 4, l16 = lane & 15;
    const int wm = wave >> 1, wn = wave & 1;
    const int tileM = blockIdx.y * 128, tileN = blockIdx.x * 128;

    auto stage2 = [&](const u16* src, int ld, int k0, u16* dst) {
        #pragma unroll
        for (int i = 0; i < 2; i++) {
            const int g = i * 256 + wave * 64 + lane;
            const int r = g >> 2;
            const int cg = (g & 3) ^ (r & 3) ^ ((r >> 2) & 3);
            gl_lds16(src + (size_t)r * ld + k0 + cg * 8,
                     dst + i * 2048 + wave * 512);
        }
    };

    f32x4 acc[4][4] = {};
    const u16* Abase = A + (size_t)tileM * lda;
    const u16* Bbase = Bm + (size_t)tileN * ldb;
    const u16* A2t = (A2a && tileN >= a2split) ? (A2b + (size_t)tileM * lda2)
                                               : (A2a ? A2a + (size_t)tileM * lda2 : nullptr);
    const u16* B2t = B2 ? B2 + (size_t)tileN * ldb2 : nullptr;
    const int slot = quad ^ (l16 & 3) ^ ((l16 >> 2) & 3);

    for (int k0 = 0; ; k0 += 32) {
        __syncthreads();
        if (k0 < K) {
            stage2(Abase, lda, k0, As);
            stage2(Bbase, ldb, k0, Bs);
        } else if (k0 == K && A2t) {
            stage2(A2t, lda2, 0, As);
            stage2(B2t, ldb2, 0, Bs);
        } else break;
        __syncthreads();
        bf16x8 af[4], bfr[4];
        #pragma unroll
        for (int mi = 0; mi < 4; mi++) {
            af[mi]  = ld8(&As[(wm * 64 + mi * 16 + l16) * 32 + slot * 8]);
            bfr[mi] = ld8(&Bs[(wn * 64 + mi * 16 + l16) * 32 + slot * 8]);
        }
        #pragma unroll
        for (int mi = 0; mi < 4; mi++)
        #pragma unroll
        for (int ni = 0; ni < 4; ni++)
            acc[mi][ni] = mfma16(af[mi], bfr[ni], acc[mi][ni]);
    }
    #pragma unroll
    for (int mi = 0; mi < 4; mi++)
    #pragma unroll
    for (int ni = 0; ni < 4; ni++)
    #pragma unroll
    for (int r = 0; r < 4; r++) {
        const int row = tileM + wm * 64 + mi * 16 + quad * 4 + r;
        const int col = tileN + wn * 64 + ni * 16 + l16;
        const size_t idx = (size_t)row * ldc + col;
        if (Cf) Cf[idx] = acc[mi][ni][r];
        else    Cb[idx] = f2bf(acc[mi][ni][r]);
    }
}

// ---------------------------------------------------------------------------
// pack: blocks [0,4096) = rope q/k per (b,t); [4096,4352) = LDS-tiled
// V transpose (b,kvh,64t x 64hd): kv_bf cols 256..511 -> vatt (b,KVH,HD,T).
// ---------------------------------------------------------------------------
__global__ __launch_bounds__(256) void pack_kernel(
    const u16* __restrict__ q_bf, const u16* __restrict__ kv_bf,
    const float* __restrict__ q_gain,
    u16* __restrict__ qatt, u16* __restrict__ katt, u16* __restrict__ vatt)
{
    __shared__ u16 tile[64][72];
    const int bx = blockIdx.x;
    const int tid = threadIdx.x;
    const float L2B = 0.41524101186092035f;   // log2(10000)/32

    if (bx < Mc) {                 // --- rope q + k ---
        const int i = bx;
        const int b = i >> 11, t = i & (Tc - 1);
        #pragma unroll
        for (int pi = tid; pi < Hc * 32; pi += 256) {
            const int h = pi >> 5, p = pi & 31;
            const float x1 = bf2f(q_bf[(size_t)i * DIMc + h * HDc + p]);
            const float x2 = bf2f(q_bf[(size_t)i * DIMc + h * HDc + 32 + p]);
            const float fr = (float)t * exp2f(-L2B * (float)p);
            float s, c; __sincosf(fr, &s, &c);
            const float g = q_gain[h] * 0.125f;
            const size_t o = ((size_t)(b * Hc + h) * Tc + t) * HDc + p;
            qatt[o]      = f2bf((x1 * c + x2 * s) * g);
            qatt[o + 32] = f2bf((x2 * c - x1 * s) * g);
        }
        if (tid < KVHc * 32) {
            const int kh = tid >> 5, p = tid & 31;
            const float x1 = bf2f(kv_bf[(size_t)i * 512 + kh * HDc + p]);
            const float x2 = bf2f(kv_bf[(size_t)i * 512 + kh * HDc + 32 + p]);
            const float fr = (float)t * exp2f(-L2B * (float)p);
            float s, c; __sincosf(fr, &s, &c);
            const size_t o = ((size_t)(b * KVHc + kh) * Tc + t) * HDc + p;
            katt[o]      = f2bf(x1 * c + x2 * s);
            katt[o + 32] = f2bf(x2 * c - x1 * s);
        }
        return;
    }
    // --- V transpose ---
    const int bi = bx - Mc;             // [0,256)
    const int bkvh = bi >> 5, tt = bi & 31;
    const int b = bkvh >> 2, kvh = bkvh & 3;
    const int t0 = tt * 64;
    {
        const int tr = tid >> 2, hd0 = (tid & 3) * 16;
        const u16* src = kv_bf + (size_t)(b * Tc + t0 + tr) * 512 + 256 + kvh * 64 + hd0;
        short8 v0 = *(const short8*)src;
        short8 v1 = *(const short8*)(src + 8);
        *(short8*)&tile[tr][hd0]     = v0;
        *(short8*)&tile[tr][hd0 + 8] = v1;
    }
    __syncthreads();
    {
        const int hd = tid >> 2, tc0 = (tid & 3) * 16;
        u16 vals[16];
        #pragma unroll
        for (int j = 0; j < 16; j++) vals[j] = tile[tc0 + j][hd];
        u16* dst = vatt + ((size_t)(b * KVHc + kvh) * HDc + hd) * Tc + t0 + tc0;
        *(short8*)dst       = *(short8*)&vals[0];
        *(short8*)(dst + 8) = *(short8*)&vals[8];
    }
}

// ---------------------------------------------------------------------------
// Flash attention v4. Same structure as v3 (64 consecutive q rows per block,
// K/V 64x64 tiles double-buffered in LDS via global_load_lds, XOR swizzle,
// S^T = K Q^T with in-lane softmax, O^T = V P^T) PLUS a balanced qtile
// schedule: co-resident blocks {id, id+256, id+512, id+768} share x and have
// (y>>3) in {0,1,2,3}, so mapping {x, 31-x, (x+8)%32, 31-(x+8)%32} gives
// every CU exactly 66 iterations of work (was: 4 identical blocks -> 2x tail).
// ---------------------------------------------------------------------------
__global__ __launch_bounds__(256) void flash_attn4(
    const u16* __restrict__ qatt, const u16* __restrict__ katt,
    const u16* __restrict__ vatt, const float* __restrict__ head_gate,
    u16* __restrict__ ybf)
{
    __shared__ __align__(16) u16 sm[20480];   // [0,8192)=Kdbuf [8192,16384)=Vdbuf [16384,20480)=P
    const int tid = threadIdx.x;
    const int wv = tid >> 6, lane = tid & 63;
    const int quad = lane >> 4, l16 = lane & 15;
    const int sw = l16 & 7;
    const int bh = blockIdx.y;
    const int b = bh >> 4, h = bh & 15;
    const int kvh = h >> 2;
    const int x = blockIdx.x, s = bh >> 3;
    int qtile;
    if      (s == 0) qtile = x;
    else if (s == 1) qtile = 31 - x;
    else if (s == 2) qtile = (x + 8) & 31;
    else             qtile = 31 - ((x + 8) & 31);
    const int qb = qtile * 64;
    const int qw = qb + wv * 16;
    const int nkt = qtile + 1;

    const u16* qbase = qatt + ((size_t)((b * Hc + h) * Tc + qw + l16)) * HDc;
    const bf16x8 bq0 = ld8(qbase + quad * 8);
    const bf16x8 bq1 = ld8(qbase + 32 + quad * 8);

    const u16* kbase = katt + (size_t)(b * KVHc + kvh) * Tc * HDc;
    const u16* vbase = vatt + (size_t)(b * KVHc + kvh) * HDc * Tc;

    auto stage = [&](int k0, int bb) {
        #pragma unroll
        for (int i = 0; i < 2; i++) {
            const int g = wv * 128 + i * 64 + lane;
            const int r = g >> 3;
            const int cg = (g & 7) ^ (r & 7);
            gl_lds16(kbase + (size_t)(k0 + r) * HDc + cg * 8,
                     &sm[bb * 4096 + wv * 1024 + i * 512]);
            gl_lds16(vbase + (size_t)r * Tc + k0 + cg * 8,
                     &sm[8192 + bb * 4096 + wv * 1024 + i * 512]);
        }
    };

    float m_run = -3.0e38f, l_run = 0.f;
    f32x4 o[4] = {};
    u16* pw = &sm[16384 + wv * 1024];

    stage(0, 0);
    for (int kt = 0; kt < nkt; kt++) {
        const int bb = kt & 1;
        __syncthreads();
        if (kt + 1 < nkt) stage((kt + 1) * 64, bb ^ 1);

        const u16* Kb = &sm[bb * 4096];
        const u16* Vb = &sm[8192 + bb * 4096];
        f32x4 st[4];
        #pragma unroll
        for (int ft = 0; ft < 4; ft++) {
            const u16* kp = Kb + (ft * 16 + l16) * 64;
            bf16x8 a0 = ld8(kp + ((quad ^ sw) << 3));
            bf16x8 a1 = ld8(kp + (((quad + 4) ^ sw) << 3));
            f32x4 sacc = {};
            sacc = mfma16(a0, bq0, sacc);
            sacc = mfma16(a1, bq1, sacc);
            st[ft] = sacc;
        }
        if (kt == nkt - 1) {
            const int qloc = wv * 16 + l16;
            #pragma unroll
            for (int ft = 0; ft < 4; ft++)
                #pragma unroll
                for (int r = 0; r < 4; r++)
                    if (ft * 16 + quad * 4 + r > qloc) st[ft][r] = -1e30f;
        }
        float vm = fmaxf(fmaxf(st[0][0], st[0][1]), fmaxf(st[0][2], st[0][3]));
        #pragma unroll
        for (int ft = 1; ft < 4; ft++)
            vm = fmaxf(vm, fmaxf(fmaxf(st[ft][0], st[ft][1]),
                                 fmaxf(st[ft][2], st[ft][3])));
        vm = fmaxf(vm, __shfl_xor(vm, 16));
        vm = fmaxf(vm, __shfl_xor(vm, 32));
        const float mnew = fmaxf(m_run, vm);
        const float alpha = __expf(m_run - mnew);
        m_run = mnew;

        float psum = 0.f;
        #pragma unroll
        for (int ft = 0; ft < 4; ft++) {
            float p0 = __expf(st[ft][0] - mnew);
            float p1 = __expf(st[ft][1] - mnew);
            float p2 = __expf(st[ft][2] - mnew);
            float p3 = __expf(st[ft][3] - mnew);
            psum += (p0 + p1) + (p2 + p3);
            u16x4 pk = {f2bf(p0), f2bf(p1), f2bf(p2), f2bf(p3)};
            const int c = (ft << 1) + (quad >> 1);
            *(u16x4*)&pw[(l16 << 6) + ((c ^ sw) << 3) + ((quad & 1) << 2)] = pk;
        }
        psum += __shfl_xor(psum, 16);
        psum += __shfl_xor(psum, 32);
        l_run = l_run * alpha + psum;

        #pragma unroll
        for (int f = 0; f < 4; f++) {
            o[f][0] *= alpha; o[f][1] *= alpha;
            o[f][2] *= alpha; o[f][3] *= alpha;
        }
        const bf16x8 pa0 = ld8(&pw[(l16 << 6) + ((quad ^ sw) << 3)]);
        const bf16x8 pa1 = ld8(&pw[(l16 << 6) + (((quad + 4) ^ sw) << 3)]);
        #pragma unroll
        for (int f = 0; f < 4; f++) {
            const u16* vp = Vb + (f * 16 + l16) * 64;
            bf16x8 v0 = ld8(vp + ((quad ^ sw) << 3));
            bf16x8 v1 = ld8(vp + (((quad + 4) ^ sw) << 3));
            o[f] = mfma16(v0, pa0, o[f]);
            o[f] = mfma16(v1, pa1, o[f]);
        }
    }
    const float inv = head_gate[h] / l_run;
    u16* yb = ybf + ((size_t)(b * Tc + qw + l16)) * DIMc + h * HDc + quad * 4;
    #pragma unroll
    for (int f = 0; f < 4; f++) {
        u16x4 pk = {f2bf(o[f][0] * inv), f2bf(o[f][1] * inv),
                    f2bf(o[f][2] * inv), f2bf(o[f][3] * inv)};
        *(u16x4*)(yb + f * 16) = pk;
    }
}

// ---------------------------------------------------------------------------
extern "C" void kernel_launch(void* const* d_in, const int* in_sizes, int n_in,
                              void* d_out, int out_size, void* d_ws, size_t ws_size,
                              hipStream_t stream) {
    (void)in_sizes; (void)n_in; (void)out_size; (void)ws_size;
    const float* x    = (const float*)d_in[0];
    const float* Wq   = (const float*)d_in[1];
    const float* Wk   = (const float*)d_in[2];
    const float* Wv   = (const float*)d_in[3];
    const float* Wo   = (const float*)d_in[4];
    const float* qA   = (const float*)d_in[5];
    const float* qB   = (const float*)d_in[6];
    const float* kA   = (const float*)d_in[7];
    const float* kB   = (const float*)d_in[8];
    const float* vA   = (const float*)d_in[9];
    const float* vB   = (const float*)d_in[10];
    const float* pA   = (const float*)d_in[11];
    const float* pB   = (const float*)d_in[12];
    const float* q_gain    = (const float*)d_in[13];
    const float* head_gate = (const float*)d_in[14];
    float* out = (float*)d_out;

    char* wsp = (char*)d_ws;
    size_t off = 0;
    auto alloc = [&](size_t bytes) -> void* {
        void* p = wsp + off;
        off = (off + bytes + 255) & ~(size_t)255;
        return p;
    };
    u16* x_bf   = (u16*)alloc((size_t)Mc * DIMc * 2);
    u16* Wq_b   = (u16*)alloc((size_t)DIMc * DIMc * 2);
    u16* Wkv_b  = (u16*)alloc((size_t)512 * DIMc * 2);
    u16* Wo_b   = (u16*)alloc((size_t)DIMc * DIMc * 2);
    u16* AT_all = (u16*)alloc((size_t)96 * 1024 * 2);
    u16* pAT    = (u16*)alloc((size_t)32 * 1024 * 2);
    u16* qBT    = (u16*)alloc((size_t)1024 * 32 * 2);
    u16* kvBT   = (u16*)alloc((size_t)512 * 32 * 2);
    u16* pBT    = (u16*)alloc((size_t)1024 * 32 * 2);
    u16* xA     = (u16*)alloc((size_t)Mc * 96 * 2);
    u16* q_bf   = (u16*)alloc((size_t)Mc * DIMc * 2);
    u16* kv_bf  = (u16*)alloc((size_t)Mc * 512 * 2);
    u16* qatt   = (u16*)alloc((size_t)Mc * DIMc * 2);
    u16* katt   = (u16*)alloc((size_t)Mc * 256 * 2);
    u16* vatt   = (u16*)alloc((size_t)Mc * 256 * 2);
    u16* y_bf   = (u16*)alloc((size_t)Mc * DIMc * 2);
    u16* yA     = (u16*)alloc((size_t)Mc * 32 * 2);

    prep_kernel<<<7680, 256, 0, stream>>>(x, Wq, Wk, Wv, Wo, qA, kA, vA, pA,
                                          qB, kB, vB, pB, x_bf,
                                          Wq_b, Wkv_b, Wo_b,
                                          AT_all, pAT, qBT, kvBT, pBT);

    // xA = x @ [qA|kA|vA]  (M=4096, N=96, K=1024)
    gemm64<<<dim3(2, 64), 256, 0, stream>>>(x_bf, DIMc, AT_all, 1024, 96, 1024, xA, 96);

    // q = x @ Wq_deq^T + xA[:, 0:32] @ qB
    gemm128<<<dim3(8, 32), 256, 0, stream>>>(x_bf, DIMc, Wq_b, DIMc, 1024,
                                             xA, xA, 1 << 30, 96, qBT, 32,
                                             nullptr, q_bf, DIMc);
    // kv = x @ Wkv_deq^T + {xA[:,32:64] @ kB | xA[:,64:96] @ vB}
    gemm128<<<dim3(4, 32), 256, 0, stream>>>(x_bf, DIMc, Wkv_b, DIMc, 1024,
                                             xA + 32, xA + 64, 256, 96, kvBT, 32,
                                             nullptr, kv_bf, 512);

    pack_kernel<<<Mc + 256, 256, 0, stream>>>(q_bf, kv_bf, q_gain, qatt, katt, vatt);

    flash_attn4<<<dim3(32, Bc * Hc), 256, 0, stream>>>(qatt, katt, vatt, head_gate, y_bf);

    // yA = y @ pA  (M=4096, N=32, K=1024)
    gemm64<<<dim3(1, 64), 256, 0, stream>>>(y_bf, DIMc, pAT, 1024, 32, 1024, yA, 32);

    // out = y @ Wo_deq^T + yA @ pB
    gemm128<<<dim3(8, 32), 256, 0, stream>>>(y_bf, DIMc, Wo_b, DIMc, 1024,
                                             yA, yA, 1 << 30, 32, pBT, 32,
                                             out, nullptr, DIMc);
}

// Round 5
// 237.762 us; speedup vs baseline: 2.0773x; 1.2700x over previous
//
#include <hip/hip_runtime.h>
#include <hip/hip_fp16.h>

#define Bc   2
#define Tc   2048
#define DIMc 1024
#define Hc   16
#define KVHc 4
#define HDc  64
#define Mc   4096   // B*T

typedef unsigned short u16;
typedef __attribute__((ext_vector_type(8))) short short8;
typedef __attribute__((ext_vector_type(8))) __bf16 bf16x8;
typedef __attribute__((ext_vector_type(4))) float f32x4;
typedef __attribute__((ext_vector_type(4))) unsigned short u16x4;

typedef const __attribute__((address_space(1))) void* gas_t;
typedef __attribute__((address_space(3))) void* las_t;

#define L2E 1.4426950408889634f
#define L2B 0.41524101186092035f   // log2(10000)/32

__device__ inline float bf2f(u16 u) {
    unsigned int x = ((unsigned int)u) << 16;
    return __builtin_bit_cast(float, x);
}
__device__ inline u16 f2bf(float f) {  // RNE
    unsigned int x = __builtin_bit_cast(unsigned int, f);
    x += 0x7fffu + ((x >> 16) & 1u);
    return (u16)(x >> 16);
}
__device__ inline bf16x8 ld8(const u16* p) {
    return __builtin_bit_cast(bf16x8, *(const short8*)p);
}
__device__ inline f32x4 mfma16(bf16x8 a, bf16x8 b, f32x4 c) {
    return __builtin_amdgcn_mfma_f32_16x16x32_bf16(a, b, c, 0, 0, 0);
}
__device__ inline void gl_lds16(const u16* g, u16* l) {
    __builtin_amdgcn_global_load_lds((gas_t)g, (las_t)l, 16, 0, 0);
}

// ---------------------------------------------------------------------------
// prep: blocks [0,1024) transposes, [1024,5120) x cast, [5120,7680) quant.
// Wqkv_b rows: 0-1023 Wq, 1024-1279 Wk, 1280-1535 Wv. qkvBT rows likewise.
// ---------------------------------------------------------------------------
__device__ inline float block_sum(float v, volatile float* red) {
    #pragma unroll
    for (int off = 32; off; off >>= 1) v += __shfl_xor(v, off);
    __syncthreads();
    if ((threadIdx.x & 63) == 0) red[threadIdx.x >> 6] = v;
    __syncthreads();
    return red[0] + red[1] + red[2] + red[3];
}
__device__ inline float block_max(float v, volatile float* red) {
    #pragma unroll
    for (int off = 32; off; off >>= 1) v = fmaxf(v, __shfl_xor(v, off));
    __syncthreads();
    if ((threadIdx.x & 63) == 0) red[threadIdx.x >> 6] = v;
    __syncthreads();
    return fmaxf(fmaxf(red[0], red[1]), fmaxf(red[2], red[3]));
}

__global__ __launch_bounds__(256) void prep_kernel(
    const float* __restrict__ x,
    const float* __restrict__ Wq, const float* __restrict__ Wk,
    const float* __restrict__ Wv, const float* __restrict__ Wo,
    const float* __restrict__ qA, const float* __restrict__ kA,
    const float* __restrict__ vA, const float* __restrict__ pA,
    const float* __restrict__ qB, const float* __restrict__ kB,
    const float* __restrict__ vB, const float* __restrict__ pB,
    u16* __restrict__ x_bf,
    u16* __restrict__ Wqkv_b, u16* __restrict__ Wo_b,
    u16* __restrict__ AT_all, u16* __restrict__ pAT,
    u16* __restrict__ qkvBT, u16* __restrict__ pBT)
{
    __shared__ float red[4];
    const int bx = blockIdx.x;
    const int tid = threadIdx.x;

    if (bx < 1024) {                       // --- small transposes ---
        const int seg = bx >> 7;
        const float* src; u16* dst; int R, C;
        switch (seg) {
            case 0: src = qA; dst = AT_all;              R = 1024; C = 32;  break;
            case 1: src = kA; dst = AT_all + 32 * 1024;  R = 1024; C = 32;  break;
            case 2: src = vA; dst = AT_all + 64 * 1024;  R = 1024; C = 32;  break;
            case 3: src = pA; dst = pAT;                 R = 1024; C = 32;  break;
            case 4: src = qB; dst = qkvBT;               R = 32; C = 1024;  break;
            case 5: src = kB; dst = qkvBT + 1024 * 32;   R = 32; C = 256;   break;
            case 6: src = vB; dst = qkvBT + 1280 * 32;   R = 32; C = 256;   break;
            default: src = pB; dst = pBT;                R = 32; C = 1024;  break;
        }
        const int idx = (bx & 127) * 256 + tid;
        if (idx < R * C) {
            const int r = idx / C, c = idx % C;
            dst[(size_t)c * R + r] = f2bf(src[(size_t)r * C + c]);
        }
        return;
    }
    if (bx < 5120) {                       // --- x fp32 -> bf16 ---
        const int i = (bx - 1024) * 256 + tid;
        float4 v = ((const float4*)x)[i];
        u16x4 o = {f2bf(v.x), f2bf(v.y), f2bf(v.z), f2bf(v.w)};
        ((u16x4*)x_bf)[i] = o;
        return;
    }
    // --- int6 RTN fake-quant, one block per weight row ---
    const int rblk = bx - 5120;
    const float* src; u16* dst;
    if (rblk < 1024)      { src = Wq + (size_t)rblk * DIMc;          dst = Wqkv_b + (size_t)rblk * DIMc; }
    else if (rblk < 1280) { src = Wk + (size_t)(rblk - 1024) * DIMc; dst = Wqkv_b + (size_t)rblk * DIMc; }
    else if (rblk < 1536) { src = Wv + (size_t)(rblk - 1280) * DIMc; dst = Wqkv_b + (size_t)rblk * DIMc; }
    else                  { src = Wo + (size_t)(rblk - 1536) * DIMc; dst = Wo_b + (size_t)(rblk - 1536) * DIMc; }

    float4 fv = ((const float4*)src)[tid];
    float tv[4] = {fv.x, fv.y, fv.z, fv.w};
    float ps = tv[0] + tv[1] + tv[2] + tv[3];
    float pa = fmaxf(fmaxf(fabsf(tv[0]), fabsf(tv[1])),
                     fmaxf(fabsf(tv[2]), fabsf(tv[3])));
    const float sum  = block_sum(ps, red);
    const float amax = block_max(pa, red);
    const float mean = sum * (1.0f / 1024.0f);
    float psq = 0.f;
    #pragma unroll
    for (int j = 0; j < 4; j++) { float d = tv[j] - mean; psq += d * d; }
    const float var  = block_sum(psq, red) * (1.0f / 1024.0f);
    const float row_std    = fmaxf(sqrtf(var), 1e-8f);
    const float row_absmax = fmaxf(amax, 1.0f / 31.0f);
    const float s1 = fmaxf(fmaxf(row_std * 12.85f, row_absmax * (1.0f / 31.0f)) * (1.0f / 31.0f),
                           1.0f / 31.0f);
    const float s2 = fmaxf(row_absmax * (1.0f / 31.0f), 1.0f / 31.0f);
    float pe1 = 0.f, pe2 = 0.f;
    #pragma unroll
    for (int j = 0; j < 4; j++) {
        float q1 = fminf(fmaxf(rintf(tv[j] / s1), -31.f), 31.f);
        float q2 = fminf(fmaxf(rintf(tv[j] / s2), -31.f), 31.f);
        float d1 = q1 * s1 - tv[j], d2 = q2 * s2 - tv[j];
        pe1 += d1 * d1; pe2 += d2 * d2;
    }
    const float e1 = block_sum(pe1, red);
    const float e2 = block_sum(pe2, red);
    const float ss = (e1 < e2) ? s1 : s2;
    const float sh = __half2float(__float2half(ss));
    u16x4 outv;
    #pragma unroll
    for (int j = 0; j < 4; j++) {
        float q = fminf(fmaxf(rintf(tv[j] / ss), -31.f), 31.f);
        outv[j] = f2bf(q * sh);
    }
    ((u16x4*)dst)[tid] = outv;
}

// ---------------------------------------------------------------------------
// gemm64p: C[M,N] = A[M,K] @ B[N,K]^T, bf16 out, register-prefetched staging
// (next tile's global loads issue before this tile's MFMA consume).
// ---------------------------------------------------------------------------
__global__ __launch_bounds__(256) void gemm64p(
    const u16* __restrict__ A, int lda,
    const u16* __restrict__ Bm, int ldb,
    int N, int K, u16* __restrict__ Cb, int ldc)
{
    __shared__ __align__(16) u16 As[64 * 40];
    __shared__ __align__(16) u16 Bs[64 * 40];
    const int tid  = threadIdx.x;
    const int wave = tid >> 6, lane = tid & 63;
    const int quad = lane >> 4, l16 = lane & 15;
    const int wm = wave >> 1, wn = wave & 1;
    const int tileM = blockIdx.y * 64;
    const int tileN = blockIdx.x * 64;
    const int lrow = tid >> 2;
    const int lcol = (tid & 3) * 8;

    f32x4 acc[2][2] = {};
    const u16* Aptr = A + (size_t)(tileM + lrow) * lda + lcol;
    const u16* Bptr = Bm + (size_t)(tileN + lrow) * ldb + lcol;
    const bool bvalid = (tileN + lrow) < N;

    short8 av = *(const short8*)Aptr;
    short8 bv = {};
    if (bvalid) bv = *(const short8*)Bptr;

    for (int k0 = 0; k0 < K; k0 += 32) {
        __syncthreads();
        *(short8*)&As[lrow * 40 + lcol] = av;
        *(short8*)&Bs[lrow * 40 + lcol] = bv;
        __syncthreads();
        if (k0 + 32 < K) {
            av = *(const short8*)(Aptr + k0 + 32);
            if (bvalid) bv = *(const short8*)(Bptr + k0 + 32);
        }
        bf16x8 a0 = ld8(&As[(wm * 32 + l16) * 40 + quad * 8]);
        bf16x8 a1 = ld8(&As[(wm * 32 + 16 + l16) * 40 + quad * 8]);
        bf16x8 b0 = ld8(&Bs[(wn * 32 + l16) * 40 + quad * 8]);
        bf16x8 b1 = ld8(&Bs[(wn * 32 + 16 + l16) * 40 + quad * 8]);
        acc[0][0] = mfma16(a0, b0, acc[0][0]);
        acc[0][1] = mfma16(a0, b1, acc[0][1]);
        acc[1][0] = mfma16(a1, b0, acc[1][0]);
        acc[1][1] = mfma16(a1, b1, acc[1][1]);
    }
    #pragma unroll
    for (int mi = 0; mi < 2; mi++)
    #pragma unroll
    for (int ni = 0; ni < 2; ni++)
    #pragma unroll
    for (int r = 0; r < 4; r++) {
        const int row = tileM + wm * 32 + mi * 16 + quad * 4 + r;
        const int col = tileN + wn * 32 + ni * 16 + l16;
        if (col < N)
            Cb[(size_t)row * ldc + col] = f2bf(acc[mi][ni][r]);
    }
}

// ---------------------------------------------------------------------------
// gemm128: C = A[M,K] @ B[N,K]^T + LoRA K2=32 tail. 128x128 tile, 4 waves.
// DOUBLE-BUFFERED global_load_lds staging (prefetch next K-tile before
// consuming current; barrier at loop top drains only the tile being consumed).
// mode 0: fp32 store to Cf.
// mode 2: fused QKV epilogue — q tiles: RoPE + gain*0.125*log2e -> qatt
//   (b,h,hd,t); k tiles: RoPE -> katt (b,kvh,t,hd); v tiles -> vatt
//   (b,kvh,hd,t) (in-register transpose, u16x4 along t).
// ---------------------------------------------------------------------------
__global__ __launch_bounds__(256) void gemm128(
    const u16* __restrict__ A, int lda,
    const u16* __restrict__ Bm, int ldb, int K,
    const u16* __restrict__ A2base, int lda2,
    const u16* __restrict__ B2base, int ldb2,
    int mode, float* __restrict__ Cf, int ldc,
    const float* __restrict__ q_gain,
    u16* __restrict__ qatt, u16* __restrict__ katt, u16* __restrict__ vatt)
{
    __shared__ __align__(16) u16 As[2][4096];
    __shared__ __align__(16) u16 Bs[2][4096];
    const int tid = threadIdx.x;
    const int wave = tid >> 6, lane = tid & 63;
    const int quad = lane >> 4, l16 = lane & 15;
    const int wm = wave >> 1, wn = wave & 1;
    const int tileM = blockIdx.y * 128, tileN = blockIdx.x * 128;

    const u16* Abase = A + (size_t)tileM * lda;
    const u16* Bbase = Bm + (size_t)tileN * ldb;
    const int a2off = (mode == 2) ? (tileN < 1024 ? 0 : (tileN < 1280 ? 32 : 64)) : 0;
    const u16* A2t = A2base + (size_t)tileM * lda2 + a2off;
    const u16* B2t = B2base + (size_t)tileN * ldb2;

    auto stage2 = [&](const u16* src, int ld, int k0, u16* dst) {
        #pragma unroll
        for (int i = 0; i < 2; i++) {
            const int g = i * 256 + wave * 64 + lane;
            const int r = g >> 2;
            const int cg = (g & 3) ^ (r & 3) ^ ((r >> 2) & 3);
            gl_lds16(src + (size_t)r * ld + k0 + cg * 8,
                     dst + i * 2048 + wave * 512);
        }
    };
    auto stage_it = [&](int it, int buf) {
        if (it < K / 32) {
            stage2(Abase, lda, it * 32, As[buf]);
            stage2(Bbase, ldb, it * 32, Bs[buf]);
        } else {
            stage2(A2t, lda2, 0, As[buf]);
            stage2(B2t, ldb2, 0, Bs[buf]);
        }
    };

    const int niter = K / 32 + 1;   // +1 LoRA tail
    const int slot = quad ^ (l16 & 3) ^ ((l16 >> 2) & 3);
    f32x4 acc[4][4] = {};

    stage_it(0, 0);
    for (int it = 0; it < niter; it++) {
        const int buf = it & 1;
        __syncthreads();                       // drains stage_it(it)
        if (it + 1 < niter) stage_it(it + 1, buf ^ 1);
        bf16x8 af[4], bfr[4];
        #pragma unroll
        for (int mi = 0; mi < 4; mi++) {
            af[mi]  = ld8(&As[buf][(wm * 64 + mi * 16 + l16) * 32 + slot * 8]);
            bfr[mi] = ld8(&Bs[buf][(wn * 64 + mi * 16 + l16) * 32 + slot * 8]);
        }
        #pragma unroll
        for (int mi = 0; mi < 4; mi++)
        #pragma unroll
        for (int ni = 0; ni < 4; ni++)
            acc[mi][ni] = mfma16(af[mi], bfr[ni], acc[mi][ni]);
    }

    const int row0 = tileM + wm * 64;
    const int col0 = tileN + wn * 64;
    if (mode == 0) {
        #pragma unroll
        for (int mi = 0; mi < 4; mi++)
        #pragma unroll
        for (int ni = 0; ni < 4; ni++)
        #pragma unroll
        for (int r = 0; r < 4; r++)
            Cf[(size_t)(row0 + mi * 16 + quad * 4 + r) * ldc + col0 + ni * 16 + l16]
                = acc[mi][ni][r];
        return;
    }
    // mode 2: fused qkv epilogue
    const int bb = row0 >> 11;
    if (col0 < 1024) {                               // ---- q: RoPE ----
        const int hh = col0 >> 6;
        const float g = q_gain[hh] * (0.125f * L2E);
        u16* qh = qatt + (size_t)(bb * Hc + hh) * HDc * Tc;
        #pragma unroll
        for (int ni = 0; ni < 2; ni++) {
            const int p = ni * 16 + l16;
            const float infr = exp2f(-L2B * (float)p);
            #pragma unroll
            for (int mi = 0; mi < 4; mi++) {
                const int t0 = (row0 + mi * 16 + quad * 4) & (Tc - 1);
                u16x4 o1, o2;
                #pragma unroll
                for (int r = 0; r < 4; r++) {
                    const float fr = (float)(t0 + r) * infr;
                    float s, c; __sincosf(fr, &s, &c);
                    const float x1 = acc[mi][ni][r], x2 = acc[mi][ni + 2][r];
                    o1[r] = f2bf((x1 * c + x2 * s) * g);
                    o2[r] = f2bf((x2 * c - x1 * s) * g);
                }
                *(u16x4*)(qh + (size_t)p * Tc + t0)        = o1;
                *(u16x4*)(qh + (size_t)(p + 32) * Tc + t0) = o2;
            }
        }
    } else if (col0 < 1280) {                        // ---- k: RoPE ----
        const int kvh = (col0 - 1024) >> 6;
        u16* kh = katt + (size_t)(bb * KVHc + kvh) * Tc * HDc;
        #pragma unroll
        for (int ni = 0; ni < 2; ni++) {
            const int p = ni * 16 + l16;
            const float infr = exp2f(-L2B * (float)p);
            #pragma unroll
            for (int mi = 0; mi < 4; mi++) {
                #pragma unroll
                for (int r = 0; r < 4; r++) {
                    const int t = (row0 + mi * 16 + quad * 4 + r) & (Tc - 1);
                    const float fr = (float)t * infr;
                    float s, c; __sincosf(fr, &s, &c);
                    const float x1 = acc[mi][ni][r], x2 = acc[mi][ni + 2][r];
                    kh[(size_t)t * HDc + p]      = f2bf(x1 * c + x2 * s);
                    kh[(size_t)t * HDc + p + 32] = f2bf(x2 * c - x1 * s);
                }
            }
        }
    } else {                                         // ---- v: transpose ----
        const int kvh = (col0 - 1280) >> 6;
        u16* vh = vatt + (size_t)(bb * KVHc + kvh) * HDc * Tc;
        #pragma unroll
        for (int ni = 0; ni < 4; ni++) {
            const int hd = ni * 16 + l16;
            #pragma unroll
            for (int mi = 0; mi < 4; mi++) {
                const int t0 = (row0 + mi * 16 + quad * 4) & (Tc - 1);
                u16x4 ov;
                #pragma unroll
                for (int r = 0; r < 4; r++) ov[r] = f2bf(acc[mi][ni][r]);
                *(u16x4*)(vh + (size_t)hd * Tc + t0) = ov;
            }
        }
    }
}

// ---------------------------------------------------------------------------
// Flash attention v5. Grid (16, B*H); block handles q-tiles {x, 31-x}
// sequentially -> EXACTLY 33 key-tile iterations per block (uniform, no tail).
// Q in (b,h,hd,t) with gain*0.125*log2e folded -> softmax uses exp2.
// K/V 64x64 tiles double-buffered in LDS via global_load_lds + XOR swizzle.
// S^T = K Q^T (softmax per-lane, col=q); O^T = V P^T; y -> (b,t,DIM) bf16.
// ---------------------------------------------------------------------------
__global__ __launch_bounds__(256) void flash_attn5(
    const u16* __restrict__ qatt, const u16* __restrict__ katt,
    const u16* __restrict__ vatt, const float* __restrict__ head_gate,
    u16* __restrict__ ybf)
{
    __shared__ __align__(16) u16 sm[20480];   // [0,8192)=Kdbuf [8192,16384)=Vdbuf [16384,20480)=P
    const int tid = threadIdx.x;
    const int wv = tid >> 6, lane = tid & 63;
    const int quad = lane >> 4, l16 = lane & 15;
    const int sw = l16 & 7;
    const int bh = blockIdx.y;
    const int b = bh >> 4, h = bh & 15;
    const int kvh = h >> 2;
    const float gate = head_gate[h];

    const u16* qhb = qatt + (size_t)(b * Hc + h) * HDc * Tc;
    const u16* kbase = katt + (size_t)(b * KVHc + kvh) * Tc * HDc;
    const u16* vbase = vatt + (size_t)(b * KVHc + kvh) * HDc * Tc;
    u16* pw = &sm[16384 + wv * 1024];

    auto stage = [&](int k0, int bb2) {
        #pragma unroll
        for (int i = 0; i < 2; i++) {
            const int g = wv * 128 + i * 64 + lane;
            const int r = g >> 3;
            const int cg = (g & 7) ^ (r & 7);
            gl_lds16(kbase + (size_t)(k0 + r) * HDc + cg * 8,
                     &sm[bb2 * 4096 + wv * 1024 + i * 512]);
            gl_lds16(vbase + (size_t)r * Tc + k0 + cg * 8,
                     &sm[8192 + bb2 * 4096 + wv * 1024 + i * 512]);
        }
    };

    for (int ph = 0; ph < 2; ph++) {
        const int qtile = ph ? (31 - (int)blockIdx.x) : (int)blockIdx.x;
        const int qw = qtile * 64 + wv * 16;
        const int nkt = qtile + 1;

        // Q B-frags: scalar gather from (hd,t) layout (once per phase)
        short8 s0v, s1v;
        #pragma unroll
        for (int j = 0; j < 8; j++) {
            s0v[j] = (short)qhb[(size_t)(quad * 8 + j) * Tc + qw + l16];
            s1v[j] = (short)qhb[(size_t)(32 + quad * 8 + j) * Tc + qw + l16];
        }
        const bf16x8 bq0 = __builtin_bit_cast(bf16x8, s0v);
        const bf16x8 bq1 = __builtin_bit_cast(bf16x8, s1v);

        __syncthreads();            // protect LDS reuse across phases
        stage(0, 0);

        float m_run = -3.0e38f, l_run = 0.f;
        f32x4 o[4] = {};

        for (int kt = 0; kt < nkt; kt++) {
            const int bb2 = kt & 1;
            __syncthreads();
            if (kt + 1 < nkt) stage((kt + 1) * 64, bb2 ^ 1);

            const u16* Kb = &sm[bb2 * 4096];
            const u16* Vb = &sm[8192 + bb2 * 4096];
            f32x4 st[4];
            #pragma unroll
            for (int ft = 0; ft < 4; ft++) {
                const u16* kp = Kb + (ft * 16 + l16) * 64;
                bf16x8 a0 = ld8(kp + ((quad ^ sw) << 3));
                bf16x8 a1 = ld8(kp + (((quad + 4) ^ sw) << 3));
                f32x4 sacc = {};
                sacc = mfma16(a0, bq0, sacc);
                sacc = mfma16(a1, bq1, sacc);
                st[ft] = sacc;
            }
            if (kt == nkt - 1) {
                const int qloc = wv * 16 + l16;
                #pragma unroll
                for (int ft = 0; ft < 4; ft++)
                    #pragma unroll
                    for (int r = 0; r < 4; r++)
                        if (ft * 16 + quad * 4 + r > qloc) st[ft][r] = -1e30f;
            }
            float vm = fmaxf(fmaxf(st[0][0], st[0][1]), fmaxf(st[0][2], st[0][3]));
            #pragma unroll
            for (int ft = 1; ft < 4; ft++)
                vm = fmaxf(vm, fmaxf(fmaxf(st[ft][0], st[ft][1]),
                                     fmaxf(st[ft][2], st[ft][3])));
            vm = fmaxf(vm, __shfl_xor(vm, 16));
            vm = fmaxf(vm, __shfl_xor(vm, 32));
            const float mnew = fmaxf(m_run, vm);
            const float alpha = exp2f(m_run - mnew);
            m_run = mnew;

            float psum = 0.f;
            #pragma unroll
            for (int ft = 0; ft < 4; ft++) {
                float p0 = exp2f(st[ft][0] - mnew);
                float p1 = exp2f(st[ft][1] - mnew);
                float p2 = exp2f(st[ft][2] - mnew);
                float p3 = exp2f(st[ft][3] - mnew);
                psum += (p0 + p1) + (p2 + p3);
                u16x4 pk = {f2bf(p0), f2bf(p1), f2bf(p2), f2bf(p3)};
                const int c = (ft << 1) + (quad >> 1);
                *(u16x4*)&pw[(l16 << 6) + ((c ^ sw) << 3) + ((quad & 1) << 2)] = pk;
            }
            psum += __shfl_xor(psum, 16);
            psum += __shfl_xor(psum, 32);
            l_run = l_run * alpha + psum;

            #pragma unroll
            for (int f = 0; f < 4; f++) {
                o[f][0] *= alpha; o[f][1] *= alpha;
                o[f][2] *= alpha; o[f][3] *= alpha;
            }
            const bf16x8 pa0 = ld8(&pw[(l16 << 6) + ((quad ^ sw) << 3)]);
            const bf16x8 pa1 = ld8(&pw[(l16 << 6) + (((quad + 4) ^ sw) << 3)]);
            #pragma unroll
            for (int f = 0; f < 4; f++) {
                const u16* vp = Vb + (f * 16 + l16) * 64;
                bf16x8 v0 = ld8(vp + ((quad ^ sw) << 3));
                bf16x8 v1 = ld8(vp + (((quad + 4) ^ sw) << 3));
                o[f] = mfma16(v0, pa0, o[f]);
                o[f] = mfma16(v1, pa1, o[f]);
            }
        }
        const float inv = gate / l_run;
        u16* yb = ybf + ((size_t)(b * Tc + qw + l16)) * DIMc + h * HDc + quad * 4;
        #pragma unroll
        for (int f = 0; f < 4; f++) {
            u16x4 pk = {f2bf(o[f][0] * inv), f2bf(o[f][1] * inv),
                        f2bf(o[f][2] * inv), f2bf(o[f][3] * inv)};
            *(u16x4*)(yb + f * 16) = pk;
        }
    }
}

// ---------------------------------------------------------------------------
extern "C" void kernel_launch(void* const* d_in, const int* in_sizes, int n_in,
                              void* d_out, int out_size, void* d_ws, size_t ws_size,
                              hipStream_t stream) {
    (void)in_sizes; (void)n_in; (void)out_size; (void)ws_size;
    const float* x    = (const float*)d_in[0];
    const float* Wq   = (const float*)d_in[1];
    const float* Wk   = (const float*)d_in[2];
    const float* Wv   = (const float*)d_in[3];
    const float* Wo   = (const float*)d_in[4];
    const float* qA   = (const float*)d_in[5];
    const float* qB   = (const float*)d_in[6];
    const float* kA   = (const float*)d_in[7];
    const float* kB   = (const float*)d_in[8];
    const float* vA   = (const float*)d_in[9];
    const float* vB   = (const float*)d_in[10];
    const float* pA   = (const float*)d_in[11];
    const float* pB   = (const float*)d_in[12];
    const float* q_gain    = (const float*)d_in[13];
    const float* head_gate = (const float*)d_in[14];
    float* out = (float*)d_out;

    char* wsp = (char*)d_ws;
    size_t off = 0;
    auto alloc = [&](size_t bytes) -> void* {
        void* p = wsp + off;
        off = (off + bytes + 255) & ~(size_t)255;
        return p;
    };
    u16* x_bf   = (u16*)alloc((size_t)Mc * DIMc * 2);
    u16* Wqkv_b = (u16*)alloc((size_t)1536 * DIMc * 2);
    u16* Wo_b   = (u16*)alloc((size_t)DIMc * DIMc * 2);
    u16* AT_all = (u16*)alloc((size_t)96 * 1024 * 2);
    u16* pAT    = (u16*)alloc((size_t)32 * 1024 * 2);
    u16* qkvBT  = (u16*)alloc((size_t)1536 * 32 * 2);
    u16* pBT    = (u16*)alloc((size_t)1024 * 32 * 2);
    u16* xA     = (u16*)alloc((size_t)Mc * 96 * 2);
    u16* qatt   = (u16*)alloc((size_t)Mc * DIMc * 2);
    u16* katt   = (u16*)alloc((size_t)Mc * 256 * 2);
    u16* vatt   = (u16*)alloc((size_t)Mc * 256 * 2);
    u16* y_bf   = (u16*)alloc((size_t)Mc * DIMc * 2);
    u16* yA     = (u16*)alloc((size_t)Mc * 32 * 2);

    prep_kernel<<<7680, 256, 0, stream>>>(x, Wq, Wk, Wv, Wo, qA, kA, vA, pA,
                                          qB, kB, vB, pB, x_bf,
                                          Wqkv_b, Wo_b, AT_all, pAT, qkvBT, pBT);

    // xA = x @ [qA|kA|vA]  (M=4096, N=96, K=1024)
    gemm64p<<<dim3(2, 64), 256, 0, stream>>>(x_bf, DIMc, AT_all, 1024, 96, 1024, xA, 96);

    // qkv = x @ Wqkv^T + LoRA tail; fused RoPE/pack epilogue
    gemm128<<<dim3(12, 32), 256, 0, stream>>>(x_bf, DIMc, Wqkv_b, DIMc, 1024,
                                              xA, 96, qkvBT, 32,
                                              2, nullptr, 0,
                                              q_gain, qatt, katt, vatt);

    flash_attn5<<<dim3(16, Bc * Hc), 256, 0, stream>>>(qatt, katt, vatt, head_gate, y_bf);

    // yA = y @ pA  (M=4096, N=32, K=1024)
    gemm64p<<<dim3(1, 64), 256, 0, stream>>>(y_bf, DIMc, pAT, 1024, 32, 1024, yA, 32);

    // out = y @ Wo_deq^T + yA @ pB (fp32)
    gemm128<<<dim3(8, 32), 256, 0, stream>>>(y_bf, DIMc, Wo_b, DIMc, 1024,
                                             yA, 32, pBT, 32,
                                             0, out, DIMc,
                                             nullptr, nullptr, nullptr, nullptr);
}